// Round 1
// baseline (898.885 us; speedup 1.0000x reference)
//
#include <hip/hip_runtime.h>
#include <hip/hip_bf16.h>
#include <math.h>

#define NTOK 1152
#define DIM 512
#define NQKV 1536
#define DHEAD 64
#define NBH 16
#define TEXTN 128
#define IMGLEN 1024
#define SEG (NBH * NTOK * DHEAD)  // 1179648 floats

// ---------------- K1: qkv = x @ w_qkv, scatter to head layout, scale q ----
__global__ __launch_bounds__(256) void gemm_qkv_k(const float* __restrict__ X,
                                                  const float* __restrict__ W,
                                                  float* __restrict__ qh,
                                                  float* __restrict__ kh,
                                                  float* __restrict__ vh) {
    __shared__ float As[16][68];
    __shared__ float Bs[16][68];
    const int tid = threadIdx.x;
    const int tx = tid & 15, ty = tid >> 4;
    const int row0 = blockIdx.y * 64;
    const int col0 = blockIdx.x * 64;
    float acc[4][4] = {};
    for (int k0 = 0; k0 < DIM; k0 += 16) {
#pragma unroll
        for (int i = 0; i < 4; ++i) {
            int idx = tid + i * 256;
            int m = idx >> 4, kk = idx & 15;
            As[kk][m] = X[(row0 + m) * DIM + k0 + kk];
            int n2 = idx & 63, kk2 = idx >> 6;
            Bs[kk2][n2] = W[(k0 + kk2) * NQKV + col0 + n2];
        }
        __syncthreads();
#pragma unroll
        for (int kk = 0; kk < 16; ++kk) {
            float4 a4 = *(const float4*)&As[kk][ty * 4];
            float4 b4 = *(const float4*)&Bs[kk][tx * 4];
            float a[4] = {a4.x, a4.y, a4.z, a4.w};
            float b[4] = {b4.x, b4.y, b4.z, b4.w};
#pragma unroll
            for (int i = 0; i < 4; ++i)
#pragma unroll
                for (int j = 0; j < 4; ++j) acc[i][j] += a[i] * b[j];
        }
        __syncthreads();
    }
#pragma unroll
    for (int i = 0; i < 4; ++i) {
        int r = row0 + ty * 4 + i;
        int b_i = r / NTOK, t = r - b_i * NTOK;
#pragma unroll
        for (int j = 0; j < 4; ++j) {
            int c = col0 + tx * 4 + j;
            int which = c >> 9;
            int ci = c & 511;
            int h = ci >> 6, d = ci & 63;
            float val = acc[i][j];
            if (which == 0) val *= 0.125f;
            float* dst = (which == 0) ? qh : ((which == 1) ? kh : vh);
            dst[((b_i * 8 + h) * NTOK + t) * DHEAD + d] = val;
        }
    }
}

// ---------------- K2: text attention (queries = tokens 1024..1151) --------
__global__ __launch_bounds__(128) void attn_text_k(const float* __restrict__ qh,
                                                   const float* __restrict__ kh,
                                                   const float* __restrict__ vh,
                                                   float* __restrict__ attn) {
    const int bh = blockIdx.x;
    __shared__ float ks[TEXTN][68];
    __shared__ float vs[TEXTN][68];
    const float* kbase = kh + (size_t)(bh * NTOK + IMGLEN) * DHEAD;
    const float* vbase = vh + (size_t)(bh * NTOK + IMGLEN) * DHEAD;
    for (int i = 0; i < 64; ++i) {
        int idx = threadIdx.x + i * 128;
        int r = idx >> 6, d = idx & 63;
        ks[r][d] = kbase[idx];
        vs[r][d] = vbase[idx];
    }
    __syncthreads();
    const int qi = threadIdx.x;
    float q[DHEAD];
    const float* qp = qh + (size_t)(bh * NTOK + IMGLEN + qi) * DHEAD;
#pragma unroll
    for (int d = 0; d < DHEAD; ++d) q[d] = qp[d];

    float m = -1e30f;
    for (int j = 0; j < TEXTN; ++j) {
        float dot = 0.f;
#pragma unroll
        for (int dq = 0; dq < 16; ++dq) {
            float4 kv = *(const float4*)&ks[j][dq * 4];
            dot += q[dq * 4] * kv.x + q[dq * 4 + 1] * kv.y + q[dq * 4 + 2] * kv.z + q[dq * 4 + 3] * kv.w;
        }
        m = fmaxf(m, dot);
    }
    float l = 0.f;
    float out[DHEAD];
#pragma unroll
    for (int d = 0; d < DHEAD; ++d) out[d] = 0.f;
    for (int j = 0; j < TEXTN; ++j) {
        float dot = 0.f;
#pragma unroll
        for (int dq = 0; dq < 16; ++dq) {
            float4 kv = *(const float4*)&ks[j][dq * 4];
            dot += q[dq * 4] * kv.x + q[dq * 4 + 1] * kv.y + q[dq * 4 + 2] * kv.z + q[dq * 4 + 3] * kv.w;
        }
        float p = __expf(dot - m);
        l += p;
#pragma unroll
        for (int dq = 0; dq < 16; ++dq) {
            float4 vv = *(const float4*)&vs[j][dq * 4];
            out[dq * 4] += p * vv.x;
            out[dq * 4 + 1] += p * vv.y;
            out[dq * 4 + 2] += p * vv.z;
            out[dq * 4 + 3] += p * vv.w;
        }
    }
    float inv = 1.f / l;
    float* dst = attn + (size_t)(bh * NTOK + qi) * DHEAD;
#pragma unroll
    for (int d = 0; d < DHEAD; ++d) dst[d] = out[d] * inv;
}

// ---------------- K3: image attention (queries = tokens 128..1151) --------
// dots = [q . k_text (128 keys)] ++ [25 "local" slots with the reference's
// scrambled unfold: slot j, element dd reads channel d=(j*64+dd)/25 at tap
// (j*64+dd)%25; out-of-bounds taps contribute 0; mask per un-scrambled tap j].
__global__ __launch_bounds__(256) void attn_img_k(const float* __restrict__ qh,
                                                  const float* __restrict__ kh,
                                                  const float* __restrict__ vh,
                                                  float* __restrict__ attn) {
    const int bh = blockIdx.x >> 2;
    const int q0 = (blockIdx.x & 3) * 256;
    __shared__ float ks[TEXTN][68];
    __shared__ float vs[TEXTN][68];
    __shared__ float locS[25][256];
    const float* kbase = kh + (size_t)(bh * NTOK + IMGLEN) * DHEAD;
    const float* vbase = vh + (size_t)(bh * NTOK + IMGLEN) * DHEAD;
    for (int i = 0; i < 32; ++i) {
        int idx = threadIdx.x + i * 256;
        int r = idx >> 6, d = idx & 63;
        ks[r][d] = kbase[idx];
        vs[r][d] = vbase[idx];
    }
    __syncthreads();
    const int qi = q0 + threadIdx.x;  // 0..1023 image position
    const int y = qi >> 5, x = qi & 31;
    float q[DHEAD];
    const float* qp = qh + (size_t)(bh * NTOK + TEXTN + qi) * DHEAD;
#pragma unroll
    for (int d = 0; d < DHEAD; ++d) q[d] = qp[d];
    const float* kimg = kh + (size_t)(bh * NTOK + TEXTN) * DHEAD;
    const float* vimg = vh + (size_t)(bh * NTOK + TEXTN) * DHEAD;

    // pass 1: max over text dots
    float m = -1e30f;
    for (int j = 0; j < TEXTN; ++j) {
        float dot = 0.f;
#pragma unroll
        for (int dq = 0; dq < 16; ++dq) {
            float4 kv = *(const float4*)&ks[j][dq * 4];
            dot += q[dq * 4] * kv.x + q[dq * 4 + 1] * kv.y + q[dq * 4 + 2] * kv.z + q[dq * 4 + 3] * kv.w;
        }
        m = fmaxf(m, dot);
    }
    // local slots (scrambled gather), store scores to LDS
    for (int j = 0; j < 25; ++j) {
        float dot = 0.f;
#pragma unroll
        for (int dd = 0; dd < DHEAD; ++dd) {
            unsigned ch = (unsigned)(j * 64 + dd);
            unsigned d = ch / 25u;
            unsigned tap = ch - d * 25u;
            int ny = y + (int)(tap / 5u) - 2;
            int nx = x + (int)(tap % 5u) - 2;
            if (ny >= 0 && ny < 32 && nx >= 0 && nx < 32)
                dot += q[dd] * kimg[(size_t)(ny * 32 + nx) * 64 + d];
        }
        int ti = j / 5, tj = j - ti * 5;
        int my = y + ti - 2, mx = x + tj - 2;
        bool keep;
        if (my >= 0 && my < 32 && mx >= 0 && mx < 32)
            keep = (qi <= my * 32 + mx);
        else
            keep = true;  // padding tap: kidx = 1024 -> kept, dot as computed
        float score = keep ? dot : -1e30f;
        locS[j][threadIdx.x] = score;
        m = fmaxf(m, score);
    }
    // pass 2
    float l = 0.f;
    float out[DHEAD];
#pragma unroll
    for (int d = 0; d < DHEAD; ++d) out[d] = 0.f;
    for (int j = 0; j < TEXTN; ++j) {
        float dot = 0.f;
#pragma unroll
        for (int dq = 0; dq < 16; ++dq) {
            float4 kv = *(const float4*)&ks[j][dq * 4];
            dot += q[dq * 4] * kv.x + q[dq * 4 + 1] * kv.y + q[dq * 4 + 2] * kv.z + q[dq * 4 + 3] * kv.w;
        }
        float p = __expf(dot - m);
        l += p;
#pragma unroll
        for (int dq = 0; dq < 16; ++dq) {
            float4 vv = *(const float4*)&vs[j][dq * 4];
            out[dq * 4] += p * vv.x;
            out[dq * 4 + 1] += p * vv.y;
            out[dq * 4 + 2] += p * vv.z;
            out[dq * 4 + 3] += p * vv.w;
        }
    }
    for (int j = 0; j < 25; ++j) {
        float p = __expf(locS[j][threadIdx.x] - m);
        l += p;
        if (p > 0.f) {
#pragma unroll
            for (int dd = 0; dd < DHEAD; ++dd) {
                unsigned ch = (unsigned)(j * 64 + dd);
                unsigned d = ch / 25u;
                unsigned tap = ch - d * 25u;
                int ny = y + (int)(tap / 5u) - 2;
                int nx = x + (int)(tap % 5u) - 2;
                if (ny >= 0 && ny < 32 && nx >= 0 && nx < 32)
                    out[dd] += p * vimg[(size_t)(ny * 32 + nx) * 64 + d];
            }
        }
    }
    float inv = 1.f / l;
    float* dst = attn + (size_t)(bh * NTOK + TEXTN + qi) * DHEAD;
#pragma unroll
    for (int d = 0; d < DHEAD; ++d) dst[d] = out[d] * inv;
}

// ---------------- K4: Y = attn_heads @ w_out + b_out ----------------------
__global__ __launch_bounds__(256) void gemm_out_k(const float* __restrict__ attn,
                                                  const float* __restrict__ W,
                                                  const float* __restrict__ bias,
                                                  float* __restrict__ Y) {
    __shared__ float As[16][68];
    __shared__ float Bs[16][68];
    const int tid = threadIdx.x;
    const int tx = tid & 15, ty = tid >> 4;
    const int row0 = blockIdx.y * 64;
    const int col0 = blockIdx.x * 64;
    float acc[4][4] = {};
    for (int k0 = 0; k0 < DIM; k0 += 16) {
#pragma unroll
        for (int i = 0; i < 4; ++i) {
            int idx = tid + i * 256;
            int mm = idx >> 4, kk = idx & 15;
            int r = row0 + mm, c = k0 + kk;
            int b_i = r / NTOK, t = r - b_i * NTOK;
            As[kk][mm] = attn[((size_t)(b_i * 8 + (c >> 6)) * NTOK + t) * DHEAD + (c & 63)];
            int n2 = idx & 63, kk2 = idx >> 6;
            Bs[kk2][n2] = W[(k0 + kk2) * DIM + col0 + n2];
        }
        __syncthreads();
#pragma unroll
        for (int kk = 0; kk < 16; ++kk) {
            float4 a4 = *(const float4*)&As[kk][ty * 4];
            float4 b4 = *(const float4*)&Bs[kk][tx * 4];
            float a[4] = {a4.x, a4.y, a4.z, a4.w};
            float b[4] = {b4.x, b4.y, b4.z, b4.w};
#pragma unroll
            for (int i = 0; i < 4; ++i)
#pragma unroll
                for (int j2 = 0; j2 < 4; ++j2) acc[i][j2] += a[i] * b[j2];
        }
        __syncthreads();
    }
#pragma unroll
    for (int i = 0; i < 4; ++i) {
        int r = row0 + ty * 4 + i;
#pragma unroll
        for (int j = 0; j < 4; ++j) {
            int c = col0 + tx * 4 + j;
            Y[(size_t)r * DIM + c] = acc[i][j] + bias[c];
        }
    }
}

extern "C" void kernel_launch(void* const* d_in, const int* in_sizes, int n_in,
                              void* d_out, int out_size, void* d_ws, size_t ws_size,
                              hipStream_t stream) {
    const float* x = (const float*)d_in[0];
    const float* w_qkv = (const float*)d_in[1];
    const float* w_out = (const float*)d_in[2];
    const float* b_out = (const float*)d_in[3];
    float* Y = (float*)d_out;
    float* ws = (float*)d_ws;
    float* qh = ws;
    float* kh = ws + (size_t)SEG;
    float* vh = ws + 2 * (size_t)SEG;
    float* attn = ws + 3 * (size_t)SEG;

    hipLaunchKernelGGL(gemm_qkv_k, dim3(NQKV / 64, 2304 / 64), dim3(256), 0, stream,
                       x, w_qkv, qh, kh, vh);
    hipLaunchKernelGGL(attn_text_k, dim3(NBH), dim3(128), 0, stream, qh, kh, vh, attn);
    hipLaunchKernelGGL(attn_img_k, dim3(NBH * 4), dim3(256), 0, stream, qh, kh, vh, attn);
    hipLaunchKernelGGL(gemm_out_k, dim3(DIM / 64, 2304 / 64), dim3(256), 0, stream,
                       attn, w_out, b_out, Y);
}

// Round 2
// 575.264 us; speedup vs baseline: 1.5626x; 1.5626x over previous
//
#include <hip/hip_runtime.h>
#include <hip/hip_bf16.h>
#include <math.h>

#define NTOK 1152
#define DIM 512
#define NQKV 1536
#define DHEAD 64
#define NBH 16
#define TEXTN 128
#define IMGLEN 1024
#define SEG (NBH * NTOK * DHEAD)  // 1179648 floats

// ---------------- K1: qkv = x @ w_qkv, scatter to head layout, scale q ----
__global__ __launch_bounds__(256) void gemm_qkv_k(const float* __restrict__ X,
                                                  const float* __restrict__ W,
                                                  float* __restrict__ qh,
                                                  float* __restrict__ kh,
                                                  float* __restrict__ vh) {
    __shared__ float As[16][68];
    __shared__ float Bs[16][68];
    const int tid = threadIdx.x;
    const int tx = tid & 15, ty = tid >> 4;
    const int row0 = blockIdx.y * 64;
    const int col0 = blockIdx.x * 64;
    float acc[4][4] = {};
    for (int k0 = 0; k0 < DIM; k0 += 16) {
#pragma unroll
        for (int i = 0; i < 4; ++i) {
            int idx = tid + i * 256;
            int m = idx >> 4, kk = idx & 15;
            As[kk][m] = X[(row0 + m) * DIM + k0 + kk];
            int n2 = idx & 63, kk2 = idx >> 6;
            Bs[kk2][n2] = W[(k0 + kk2) * NQKV + col0 + n2];
        }
        __syncthreads();
#pragma unroll
        for (int kk = 0; kk < 16; ++kk) {
            float4 a4 = *(const float4*)&As[kk][ty * 4];
            float4 b4 = *(const float4*)&Bs[kk][tx * 4];
            float a[4] = {a4.x, a4.y, a4.z, a4.w};
            float b[4] = {b4.x, b4.y, b4.z, b4.w};
#pragma unroll
            for (int i = 0; i < 4; ++i)
#pragma unroll
                for (int j = 0; j < 4; ++j) acc[i][j] += a[i] * b[j];
        }
        __syncthreads();
    }
#pragma unroll
    for (int i = 0; i < 4; ++i) {
        int r = row0 + ty * 4 + i;
        int b_i = r / NTOK, t = r - b_i * NTOK;
#pragma unroll
        for (int j = 0; j < 4; ++j) {
            int c = col0 + tx * 4 + j;
            int which = c >> 9;
            int ci = c & 511;
            int h = ci >> 6, d = ci & 63;
            float val = acc[i][j];
            if (which == 0) val *= 0.125f;
            float* dst = (which == 0) ? qh : ((which == 1) ? kh : vh);
            dst[((b_i * 8 + h) * NTOK + t) * DHEAD + d] = val;
        }
    }
}

#define RESCALE_THR 4.0f

// ---------------- K2: text attention (queries = tokens 1024..1151) --------
// One thread per query, online softmax with deferred-max rescale.
__global__ __launch_bounds__(64) void attn_text_k(const float* __restrict__ qh,
                                                  const float* __restrict__ kh,
                                                  const float* __restrict__ vh,
                                                  float* __restrict__ attn) {
    const int bh = blockIdx.x >> 1;
    const int qi = (blockIdx.x & 1) * 64 + threadIdx.x;  // 0..127
    const float* ktext = kh + (size_t)(bh * NTOK + IMGLEN) * DHEAD;
    const float* vtext = vh + (size_t)(bh * NTOK + IMGLEN) * DHEAD;

    float q[DHEAD];
    const float* qp = qh + (size_t)(bh * NTOK + IMGLEN + qi) * DHEAD;
#pragma unroll
    for (int dg = 0; dg < 16; ++dg) {
        float4 v4 = *(const float4*)(qp + dg * 4);
        q[dg * 4] = v4.x; q[dg * 4 + 1] = v4.y; q[dg * 4 + 2] = v4.z; q[dg * 4 + 3] = v4.w;
    }
    float out[DHEAD];
#pragma unroll
    for (int d = 0; d < DHEAD; ++d) out[d] = 0.f;
    float m = -1e30f, l = 0.f;

#pragma unroll 2
    for (int j = 0; j < TEXTN; ++j) {
        const float* kp = ktext + j * DHEAD;
        float dot = 0.f;
#pragma unroll
        for (int dg = 0; dg < 16; ++dg) {
            float4 kv = *(const float4*)(kp + dg * 4);
            dot += q[dg * 4] * kv.x + q[dg * 4 + 1] * kv.y + q[dg * 4 + 2] * kv.z + q[dg * 4 + 3] * kv.w;
        }
        if (dot > m + RESCALE_THR) {
            float c = __expf(m - dot);
            l *= c;
#pragma unroll
            for (int d = 0; d < DHEAD; ++d) out[d] *= c;
            m = dot;
        }
        float p = __expf(dot - m);
        l += p;
        const float* vp = vtext + j * DHEAD;
#pragma unroll
        for (int dg = 0; dg < 16; ++dg) {
            float4 vv = *(const float4*)(vp + dg * 4);
            out[dg * 4] += p * vv.x;
            out[dg * 4 + 1] += p * vv.y;
            out[dg * 4 + 2] += p * vv.z;
            out[dg * 4 + 3] += p * vv.w;
        }
    }
    float inv = 1.f / l;
    float* dst = attn + (size_t)(bh * NTOK + qi) * DHEAD;
#pragma unroll
    for (int dg = 0; dg < 16; ++dg) {
        float4 o;
        o.x = out[dg * 4] * inv; o.y = out[dg * 4 + 1] * inv;
        o.z = out[dg * 4 + 2] * inv; o.w = out[dg * 4 + 3] * inv;
        *(float4*)(dst + dg * 4) = o;
    }
}

// ---------------- K3: image attention (queries = tokens 128..1151) --------
// One thread per query. Text keys: online softmax (deferred max). Local
// 25-slot scrambled unfold inverted to tap-major form: for compile-time
// tap t and channel d, idx=d*25+t, slot=idx>>6, q-elem=idx&63 are constants.
__global__ __launch_bounds__(64) void attn_img_k(const float* __restrict__ qh,
                                                 const float* __restrict__ kh,
                                                 const float* __restrict__ vh,
                                                 float* __restrict__ attn) {
    const int bh = blockIdx.x >> 4;
    const int qi = (blockIdx.x & 15) * 64 + threadIdx.x;  // 0..1023
    const int y = qi >> 5, x = qi & 31;
    const float* ktext = kh + (size_t)(bh * NTOK + IMGLEN) * DHEAD;
    const float* vtext = vh + (size_t)(bh * NTOK + IMGLEN) * DHEAD;
    const float* kimg = kh + (size_t)(bh * NTOK + TEXTN) * DHEAD;
    const float* vimg = vh + (size_t)(bh * NTOK + TEXTN) * DHEAD;

    float q[DHEAD];
    const float* qp = qh + (size_t)(bh * NTOK + TEXTN + qi) * DHEAD;
#pragma unroll
    for (int dg = 0; dg < 16; ++dg) {
        float4 v4 = *(const float4*)(qp + dg * 4);
        q[dg * 4] = v4.x; q[dg * 4 + 1] = v4.y; q[dg * 4 + 2] = v4.z; q[dg * 4 + 3] = v4.w;
    }
    float out[DHEAD];
#pragma unroll
    for (int d = 0; d < DHEAD; ++d) out[d] = 0.f;
    float m = -1e30f, l = 0.f;

    // ---- text keys, online ----
#pragma unroll 2
    for (int j = 0; j < TEXTN; ++j) {
        const float* kp = ktext + j * DHEAD;
        float dot = 0.f;
#pragma unroll
        for (int dg = 0; dg < 16; ++dg) {
            float4 kv = *(const float4*)(kp + dg * 4);
            dot += q[dg * 4] * kv.x + q[dg * 4 + 1] * kv.y + q[dg * 4 + 2] * kv.z + q[dg * 4 + 3] * kv.w;
        }
        if (dot > m + RESCALE_THR) {
            float c = __expf(m - dot);
            l *= c;
#pragma unroll
            for (int d = 0; d < DHEAD; ++d) out[d] *= c;
            m = dot;
        }
        float p = __expf(dot - m);
        l += p;
        const float* vp = vtext + j * DHEAD;
#pragma unroll
        for (int dg = 0; dg < 16; ++dg) {
            float4 vv = *(const float4*)(vp + dg * 4);
            out[dg * 4] += p * vv.x;
            out[dg * 4 + 1] += p * vv.y;
            out[dg * 4 + 2] += p * vv.z;
            out[dg * 4 + 3] += p * vv.w;
        }
    }

    // ---- local 25 slots: tap-major scrambled dot ----
    float dots[25];
#pragma unroll
    for (int j = 0; j < 25; ++j) dots[j] = 0.f;
#pragma unroll
    for (int t = 0; t < 25; ++t) {
        const int ny = y + t / 5 - 2;
        const int nx = x + t % 5 - 2;
        if (ny >= 0 && ny < 32 && nx >= 0 && nx < 32) {
            const float* kp = kimg + (size_t)(ny * 32 + nx) * DHEAD;
#pragma unroll
            for (int dg = 0; dg < 16; ++dg) {
                float4 kv = *(const float4*)(kp + dg * 4);
                float ke[4] = {kv.x, kv.y, kv.z, kv.w};
#pragma unroll
                for (int e = 0; e < 4; ++e) {
                    const int d = dg * 4 + e;
                    const int idx = d * 25 + t;
                    dots[idx >> 6] += q[idx & 63] * ke[e];
                }
            }
        }
    }
    // ---- mask (slot j uses tap-j geometry) + local max ----
    float mloc = -1e30f;
#pragma unroll
    for (int j = 0; j < 25; ++j) {
        const int my = y + j / 5 - 2;
        const int mx = x + j % 5 - 2;
        bool inb = (my >= 0 && my < 32 && mx >= 0 && mx < 32);
        bool keep = inb ? (qi <= my * 32 + mx) : true;
        dots[j] = keep ? dots[j] : -1e30f;
        mloc = fmaxf(mloc, dots[j]);
    }
    // ---- merge local into running softmax ----
    float newm = fmaxf(m, mloc);
    {
        float c = __expf(m - newm);
        l *= c;
#pragma unroll
        for (int d = 0; d < DHEAD; ++d) out[d] *= c;
    }
#pragma unroll
    for (int j = 0; j < 25; ++j) {
        float p = __expf(dots[j] - newm);
        l += p;
        dots[j] = p;
    }
    // ---- local PV, tap-major ----
#pragma unroll
    for (int t = 0; t < 25; ++t) {
        const int ny = y + t / 5 - 2;
        const int nx = x + t % 5 - 2;
        if (ny >= 0 && ny < 32 && nx >= 0 && nx < 32) {
            const float* vp = vimg + (size_t)(ny * 32 + nx) * DHEAD;
#pragma unroll
            for (int dg = 0; dg < 16; ++dg) {
                float4 vv = *(const float4*)(vp + dg * 4);
                float ve[4] = {vv.x, vv.y, vv.z, vv.w};
#pragma unroll
                for (int e = 0; e < 4; ++e) {
                    const int d = dg * 4 + e;
                    const int idx = d * 25 + t;
                    out[idx & 63] += dots[idx >> 6] * ve[e];
                }
            }
        }
    }
    float inv = 1.f / l;
    float* dst = attn + (size_t)(bh * NTOK + TEXTN + qi) * DHEAD;
#pragma unroll
    for (int dg = 0; dg < 16; ++dg) {
        float4 o;
        o.x = out[dg * 4] * inv; o.y = out[dg * 4 + 1] * inv;
        o.z = out[dg * 4 + 2] * inv; o.w = out[dg * 4 + 3] * inv;
        *(float4*)(dst + dg * 4) = o;
    }
}

// ---------------- K4: Y = attn_heads @ w_out + b_out ----------------------
__global__ __launch_bounds__(256) void gemm_out_k(const float* __restrict__ attn,
                                                  const float* __restrict__ W,
                                                  const float* __restrict__ bias,
                                                  float* __restrict__ Y) {
    __shared__ float As[16][68];
    __shared__ float Bs[16][68];
    const int tid = threadIdx.x;
    const int tx = tid & 15, ty = tid >> 4;
    const int row0 = blockIdx.y * 64;
    const int col0 = blockIdx.x * 64;
    float acc[4][4] = {};
    for (int k0 = 0; k0 < DIM; k0 += 16) {
#pragma unroll
        for (int i = 0; i < 4; ++i) {
            int idx = tid + i * 256;
            int mm = idx >> 4, kk = idx & 15;
            int r = row0 + mm, c = k0 + kk;
            int b_i = r / NTOK, t = r - b_i * NTOK;
            As[kk][mm] = attn[((size_t)(b_i * 8 + (c >> 6)) * NTOK + t) * DHEAD + (c & 63)];
            int n2 = idx & 63, kk2 = idx >> 6;
            Bs[kk2][n2] = W[(k0 + kk2) * DIM + col0 + n2];
        }
        __syncthreads();
#pragma unroll
        for (int kk = 0; kk < 16; ++kk) {
            float4 a4 = *(const float4*)&As[kk][ty * 4];
            float4 b4 = *(const float4*)&Bs[kk][tx * 4];
            float a[4] = {a4.x, a4.y, a4.z, a4.w};
            float b[4] = {b4.x, b4.y, b4.z, b4.w};
#pragma unroll
            for (int i = 0; i < 4; ++i)
#pragma unroll
                for (int j2 = 0; j2 < 4; ++j2) acc[i][j2] += a[i] * b[j2];
        }
        __syncthreads();
    }
#pragma unroll
    for (int i = 0; i < 4; ++i) {
        int r = row0 + ty * 4 + i;
#pragma unroll
        for (int j = 0; j < 4; ++j) {
            int c = col0 + tx * 4 + j;
            Y[(size_t)r * DIM + c] = acc[i][j] + bias[c];
        }
    }
}

extern "C" void kernel_launch(void* const* d_in, const int* in_sizes, int n_in,
                              void* d_out, int out_size, void* d_ws, size_t ws_size,
                              hipStream_t stream) {
    const float* x = (const float*)d_in[0];
    const float* w_qkv = (const float*)d_in[1];
    const float* w_out = (const float*)d_in[2];
    const float* b_out = (const float*)d_in[3];
    float* Y = (float*)d_out;
    float* ws = (float*)d_ws;
    float* qh = ws;
    float* kh = ws + (size_t)SEG;
    float* vh = ws + 2 * (size_t)SEG;
    float* attn = ws + 3 * (size_t)SEG;

    hipLaunchKernelGGL(gemm_qkv_k, dim3(NQKV / 64, 2304 / 64), dim3(256), 0, stream,
                       x, w_qkv, qh, kh, vh);
    hipLaunchKernelGGL(attn_text_k, dim3(NBH * 2), dim3(64), 0, stream, qh, kh, vh, attn);
    hipLaunchKernelGGL(attn_img_k, dim3(NBH * 16), dim3(64), 0, stream, qh, kh, vh, attn);
    hipLaunchKernelGGL(gemm_out_k, dim3(DIM / 64, 2304 / 64), dim3(256), 0, stream,
                       attn, w_out, b_out, Y);
}

// Round 6
// 260.362 us; speedup vs baseline: 3.4524x; 2.2095x over previous
//
#include <hip/hip_runtime.h>
#include <hip/hip_bf16.h>
#include <math.h>

#define NTOK 1152
#define DIM 512
#define NQKV 1536
#define DHEAD 64
#define NBH 16
#define TEXTN 128
#define IMGLEN 1024
#define SEG (NBH * NTOK * DHEAD)  // 1179648 floats
#define THR 4.0f

// ---------------- K1: qkv = x @ w_qkv, scatter to head layout, scale q ----
__global__ __launch_bounds__(256) void gemm_qkv_k(const float* __restrict__ X,
                                                  const float* __restrict__ W,
                                                  float* __restrict__ qh,
                                                  float* __restrict__ kh,
                                                  float* __restrict__ vh) {
    __shared__ float As[16][68];
    __shared__ float Bs[16][68];
    const int tid = threadIdx.x;
    const int tx = tid & 15, ty = tid >> 4;
    const int row0 = blockIdx.y * 64;
    const int col0 = blockIdx.x * 64;
    float acc[4][4] = {};
    for (int k0 = 0; k0 < DIM; k0 += 16) {
#pragma unroll
        for (int i = 0; i < 4; ++i) {
            int idx = tid + i * 256;
            int m = idx >> 4, kk = idx & 15;
            As[kk][m] = X[(row0 + m) * DIM + k0 + kk];
            int n2 = idx & 63, kk2 = idx >> 6;
            Bs[kk2][n2] = W[(k0 + kk2) * NQKV + col0 + n2];
        }
        __syncthreads();
#pragma unroll
        for (int kk = 0; kk < 16; ++kk) {
            float4 a4 = *(const float4*)&As[kk][ty * 4];
            float4 b4 = *(const float4*)&Bs[kk][tx * 4];
            float a[4] = {a4.x, a4.y, a4.z, a4.w};
            float b[4] = {b4.x, b4.y, b4.z, b4.w};
#pragma unroll
            for (int i = 0; i < 4; ++i)
#pragma unroll
                for (int j = 0; j < 4; ++j) acc[i][j] += a[i] * b[j];
        }
        __syncthreads();
    }
#pragma unroll
    for (int i = 0; i < 4; ++i) {
        int r = row0 + ty * 4 + i;
        int b_i = r / NTOK, t = r - b_i * NTOK;
#pragma unroll
        for (int j = 0; j < 4; ++j) {
            int c = col0 + tx * 4 + j;
            int which = c >> 9;
            int ci = c & 511;
            int hh = ci >> 6, d = ci & 63;
            float val = acc[i][j];
            if (which == 0) val *= 0.125f;
            float* dst = (which == 0) ? qh : ((which == 1) ? kh : vh);
            dst[((b_i * 8 + hh) * NTOK + t) * DHEAD + d] = val;
        }
    }
}

// ---------------- K2: fused attention (img + text queries) ----------------
// grid = 16 bh * 36 chunks. Chunks 0..31: img queries (32/chunk); 32..35:
// text queries (32/chunk). Block = 64 threads = 1 wave; lane L handles
// query (L&31), d-half (L>>5). K_text/V_text staged in LDS.
__global__ __launch_bounds__(64, 1) void attn_k(const float* __restrict__ qh,
                                                const float* __restrict__ kh,
                                                const float* __restrict__ vh,
                                                float* __restrict__ attn) {
    const int bh = blockIdx.x / 36;
    const int c = blockIdx.x % 36;
    const bool is_img = (c < 32);
    __shared__ float ks[TEXTN * DHEAD];
    __shared__ float vs[TEXTN * DHEAD];
    {
        const float* kbase = kh + (size_t)(bh * NTOK + IMGLEN) * DHEAD;
        const float* vbase = vh + (size_t)(bh * NTOK + IMGLEN) * DHEAD;
        const int t = threadIdx.x;
#pragma unroll
        for (int i = 0; i < 32; ++i) {
            int f4 = t + i * 64;
            *(float4*)&ks[f4 * 4] = *(const float4*)&kbase[f4 * 4];
            *(float4*)&vs[f4 * 4] = *(const float4*)&vbase[f4 * 4];
        }
    }
    __syncthreads();
    const int lane = threadIdx.x;
    const int qsub = lane & 31, h = lane >> 5;
    const int hb = h * 32;
    const int qq = (is_img ? c : (c - 32)) * 32 + qsub;
    const int token = is_img ? (TEXTN + qq) : (IMGLEN + qq);
    const int row = is_img ? (TEXTN + qq) : qq;

    float q[32];
    {
        const float* qp = qh + ((size_t)(bh * NTOK + token)) * DHEAD + hb;
#pragma unroll
        for (int e4 = 0; e4 < 8; ++e4) {
            float4 v4 = *(const float4*)(qp + e4 * 4);
            q[e4 * 4] = v4.x; q[e4 * 4 + 1] = v4.y; q[e4 * 4 + 2] = v4.z; q[e4 * 4 + 3] = v4.w;
        }
    }
    float out[32];
#pragma unroll
    for (int e = 0; e < 32; ++e) out[e] = 0.f;
    float m = -1e30f, l = 0.f;

#pragma unroll 2
    for (int j = 0; j < TEXTN; ++j) {
        const float* kr = &ks[j * DHEAD + hb];
        float part = 0.f;
#pragma unroll
        for (int e4 = 0; e4 < 8; ++e4) {
            float4 kv = *(const float4*)(kr + e4 * 4);
            part += q[e4 * 4] * kv.x + q[e4 * 4 + 1] * kv.y + q[e4 * 4 + 2] * kv.z + q[e4 * 4 + 3] * kv.w;
        }
        float dot = part + __shfl_xor(part, 32);
        if (dot > m + THR) {
            float cc = __expf(m - dot);
            l *= cc;
#pragma unroll
            for (int e = 0; e < 32; ++e) out[e] *= cc;
            m = dot;
        }
        float p = __expf(dot - m);
        l += p;
        const float* vr = &vs[j * DHEAD + hb];
#pragma unroll
        for (int e4 = 0; e4 < 8; ++e4) {
            float4 vv = *(const float4*)(vr + e4 * 4);
            out[e4 * 4] += p * vv.x;
            out[e4 * 4 + 1] += p * vv.y;
            out[e4 * 4 + 2] += p * vv.z;
            out[e4 * 4 + 3] += p * vv.w;
        }
    }

    if (is_img) {
        // rebuild full q in every lane
        float qf[64];
#pragma unroll
        for (int e = 0; e < 32; ++e) {
            float r = __shfl_xor(q[e], 32);
            qf[e] = h ? r : q[e];
            qf[32 + e] = h ? q[e] : r;
        }
        const int y = qq >> 5, xx = qq & 31;
        const float* kimg = kh + (size_t)(bh * NTOK + TEXTN) * DHEAD;
        const float* vimg = vh + (size_t)(bh * NTOK + TEXTN) * DHEAD;
        float sdot[25];
#pragma unroll
        for (int j = 0; j < 25; ++j) sdot[j] = 0.f;
        float locO[64];
#pragma unroll
        for (int e = 0; e < 64; ++e) locO[e] = 0.f;
        // scrambled local dots: computed by h==0 lanes only (tap-major)
        if (h == 0) {
#pragma unroll
            for (int t = 0; t < 25; ++t) {
                const int ny = y + t / 5 - 2;
                const int nx = xx + t % 5 - 2;
                if (ny >= 0 && ny < 32 && nx >= 0 && nx < 32) {
                    const float* kp = kimg + (size_t)(ny * 32 + nx) * DHEAD;
#pragma unroll
                    for (int dg = 0; dg < 16; ++dg) {
                        float4 kv = *(const float4*)(kp + dg * 4);
                        float ke[4] = {kv.x, kv.y, kv.z, kv.w};
#pragma unroll
                        for (int e = 0; e < 4; ++e) {
                            const int d = dg * 4 + e;
                            const int idx = d * 25 + t;
                            sdot[idx >> 6] += qf[idx & 63] * ke[e];
                        }
                    }
                }
            }
        }
        // broadcast raw slot dots to h==1 lanes
#pragma unroll
        for (int j = 0; j < 25; ++j) {
            float tmp = __shfl_xor(sdot[j], 32);
            sdot[j] = h ? tmp : sdot[j];
        }
        // mask + merge into running softmax (all lanes, identical per pair)
        float mloc = -1e30f;
#pragma unroll
        for (int j = 0; j < 25; ++j) {
            const int my = y + j / 5 - 2;
            const int mx = xx + j % 5 - 2;
            bool inb = (my >= 0 && my < 32 && mx >= 0 && mx < 32);
            bool keep = inb ? (qq <= my * 32 + mx) : true;
            sdot[j] = keep ? sdot[j] : -1e30f;
            mloc = fmaxf(mloc, sdot[j]);
        }
        float newm = fmaxf(m, mloc);
        {
            float cc = __expf(m - newm);
            l *= cc;
#pragma unroll
            for (int e = 0; e < 32; ++e) out[e] *= cc;
            m = newm;
        }
#pragma unroll
        for (int j = 0; j < 25; ++j) {
            sdot[j] = __expf(sdot[j] - newm);  // becomes p_loc
            l += sdot[j];
        }
        // local PV (h==0 lanes), scrambled tap-major
        if (h == 0) {
#pragma unroll
            for (int t = 0; t < 25; ++t) {
                const int ny = y + t / 5 - 2;
                const int nx = xx + t % 5 - 2;
                if (ny >= 0 && ny < 32 && nx >= 0 && nx < 32) {
                    const float* vp = vimg + (size_t)(ny * 32 + nx) * DHEAD;
#pragma unroll
                    for (int dg = 0; dg < 16; ++dg) {
                        float4 vv = *(const float4*)(vp + dg * 4);
                        float ve[4] = {vv.x, vv.y, vv.z, vv.w};
#pragma unroll
                        for (int e = 0; e < 4; ++e) {
                            const int d = dg * 4 + e;
                            const int idx = d * 25 + t;
                            locO[idx & 63] += sdot[idx >> 6] * ve[e];
                        }
                    }
                }
            }
        }
        // exchange local-PV halves back to owners
#pragma unroll
        for (int e = 0; e < 32; ++e) {
            float send = h ? locO[e] : locO[32 + e];
            float recv = __shfl_xor(send, 32);
            float mine = h ? locO[32 + e] : locO[e];
            out[e] += mine + recv;
        }
    }

    float inv = 1.f / l;
    float* dst = attn + ((size_t)(bh * NTOK + row)) * DHEAD + hb;
#pragma unroll
    for (int e4 = 0; e4 < 8; ++e4) {
        float4 o;
        o.x = out[e4 * 4] * inv; o.y = out[e4 * 4 + 1] * inv;
        o.z = out[e4 * 4 + 2] * inv; o.w = out[e4 * 4 + 3] * inv;
        *(float4*)(dst + e4 * 4) = o;
    }
}

// ---------------- K4: Y = attn_heads @ w_out + b_out ----------------------
__global__ __launch_bounds__(256) void gemm_out_k(const float* __restrict__ attn,
                                                  const float* __restrict__ W,
                                                  const float* __restrict__ bias,
                                                  float* __restrict__ Y) {
    __shared__ float As[16][68];
    __shared__ float Bs[16][68];
    const int tid = threadIdx.x;
    const int tx = tid & 15, ty = tid >> 4;
    const int row0 = blockIdx.y * 64;
    const int col0 = blockIdx.x * 64;
    float acc[4][4] = {};
    for (int k0 = 0; k0 < DIM; k0 += 16) {
#pragma unroll
        for (int i = 0; i < 4; ++i) {
            int idx = tid + i * 256;
            int mm = idx >> 4, kk = idx & 15;
            int r = row0 + mm, cc = k0 + kk;
            int b_i = r / NTOK, t = r - b_i * NTOK;
            As[kk][mm] = attn[((size_t)(b_i * 8 + (cc >> 6)) * NTOK + t) * DHEAD + (cc & 63)];
            int n2 = idx & 63, kk2 = idx >> 6;
            Bs[kk2][n2] = W[(k0 + kk2) * DIM + col0 + n2];
        }
        __syncthreads();
#pragma unroll
        for (int kk = 0; kk < 16; ++kk) {
            float4 a4 = *(const float4*)&As[kk][ty * 4];
            float4 b4 = *(const float4*)&Bs[kk][tx * 4];
            float a[4] = {a4.x, a4.y, a4.z, a4.w};
            float b[4] = {b4.x, b4.y, b4.z, b4.w};
#pragma unroll
            for (int i = 0; i < 4; ++i)
#pragma unroll
                for (int j2 = 0; j2 < 4; ++j2) acc[i][j2] += a[i] * b[j2];
        }
        __syncthreads();
    }
#pragma unroll
    for (int i = 0; i < 4; ++i) {
        int r = row0 + ty * 4 + i;
#pragma unroll
        for (int j = 0; j < 4; ++j) {
            int cc = col0 + tx * 4 + j;
            Y[(size_t)r * DIM + cc] = acc[i][j] + bias[cc];
        }
    }
}

extern "C" void kernel_launch(void* const* d_in, const int* in_sizes, int n_in,
                              void* d_out, int out_size, void* d_ws, size_t ws_size,
                              hipStream_t stream) {
    const float* x = (const float*)d_in[0];
    const float* w_qkv = (const float*)d_in[1];
    const float* w_out = (const float*)d_in[2];
    const float* b_out = (const float*)d_in[3];
    float* Y = (float*)d_out;
    float* ws = (float*)d_ws;
    float* qh = ws;
    float* kh = ws + (size_t)SEG;
    float* vh = ws + 2 * (size_t)SEG;
    float* attn = ws + 3 * (size_t)SEG;

    hipLaunchKernelGGL(gemm_qkv_k, dim3(NQKV / 64, 2304 / 64), dim3(256), 0, stream,
                       x, w_qkv, qh, kh, vh);
    hipLaunchKernelGGL(attn_k, dim3(NBH * 36), dim3(64), 0, stream, qh, kh, vh, attn);
    hipLaunchKernelGGL(gemm_out_k, dim3(DIM / 64, 2304 / 64), dim3(256), 0, stream,
                       attn, w_out, b_out, Y);
}

// Round 7
// 209.622 us; speedup vs baseline: 4.2881x; 1.2421x over previous
//
#include <hip/hip_runtime.h>
#include <hip/hip_bf16.h>
#include <math.h>

#define NTOK 1152
#define DIM 512
#define NQKV 1536
#define DHEAD 64
#define NBH 16
#define TEXTN 128
#define IMGLEN 1024
#define SEG (NBH * NTOK * DHEAD)  // 1179648 floats
#define THR 4.0f
#define STF 68  // tstate floats per query: 64 out + m + l + pad

// ---------------- K1: qkv = x @ w_qkv, scatter to head layout, scale q ----
__global__ __launch_bounds__(256) void gemm_qkv_k(const float* __restrict__ X,
                                                  const float* __restrict__ W,
                                                  float* __restrict__ qh,
                                                  float* __restrict__ kh,
                                                  float* __restrict__ vh) {
    __shared__ float As[16][68];
    __shared__ float Bs[16][68];
    const int tid = threadIdx.x;
    const int tx = tid & 15, ty = tid >> 4;
    const int row0 = blockIdx.y * 64;
    const int col0 = blockIdx.x * 64;
    float acc[4][4] = {};
    for (int k0 = 0; k0 < DIM; k0 += 16) {
#pragma unroll
        for (int i = 0; i < 4; ++i) {
            int idx = tid + i * 256;
            int m = idx >> 4, kk = idx & 15;
            As[kk][m] = X[(row0 + m) * DIM + k0 + kk];
            int n2 = idx & 63, kk2 = idx >> 6;
            Bs[kk2][n2] = W[(k0 + kk2) * NQKV + col0 + n2];
        }
        __syncthreads();
#pragma unroll
        for (int kk = 0; kk < 16; ++kk) {
            float4 a4 = *(const float4*)&As[kk][ty * 4];
            float4 b4 = *(const float4*)&Bs[kk][tx * 4];
            float a[4] = {a4.x, a4.y, a4.z, a4.w};
            float b[4] = {b4.x, b4.y, b4.z, b4.w};
#pragma unroll
            for (int i = 0; i < 4; ++i)
#pragma unroll
                for (int j = 0; j < 4; ++j) acc[i][j] += a[i] * b[j];
        }
        __syncthreads();
    }
#pragma unroll
    for (int i = 0; i < 4; ++i) {
        int r = row0 + ty * 4 + i;
        int b_i = r / NTOK, t = r - b_i * NTOK;
#pragma unroll
        for (int j = 0; j < 4; ++j) {
            int c = col0 + tx * 4 + j;
            int which = c >> 9;
            int ci = c & 511;
            int hh = ci >> 6, d = ci & 63;
            float val = acc[i][j];
            if (which == 0) val *= 0.125f;
            float* dst = (which == 0) ? qh : ((which == 1) ? kh : vh);
            dst[((b_i * 8 + hh) * NTOK + t) * DHEAD + d] = val;
        }
    }
}

// ---------------- K2: text-key flash for ALL queries (split-K=2) ----------
// grid = 16 bh * 36 chunks, block = 128 (2 waves). Wave w handles keys
// [64w, 64w+64). Lane = qsub(0..31) + 32*h (d-half). Text K/V read directly
// from global (L2-resident, wave-uniform broadcast). Merge via LDS.
// Text queries (chunks 32..35): finalize + write attn.
// Img queries (chunks 0..31): write unnormalized state (out,m,l) to tstate.
__global__ __launch_bounds__(128) void attn_text_k(const float* __restrict__ qh,
                                                   const float* __restrict__ kh,
                                                   const float* __restrict__ vh,
                                                   float* __restrict__ attn,
                                                   float* __restrict__ tstate) {
    const int bh = blockIdx.x / 36;
    const int c = blockIdx.x % 36;
    const bool is_img = (c < 32);
    const int wave = threadIdx.x >> 6;
    const int lane = threadIdx.x & 63;
    const int qsub = lane & 31, h = lane >> 5;
    const int hb = h * 32;
    const int qq = (is_img ? c : (c - 32)) * 32 + qsub;
    const int token = is_img ? (TEXTN + qq) : (IMGLEN + qq);
    const float* ktext = kh + (size_t)(bh * NTOK + IMGLEN) * DHEAD;
    const float* vtext = vh + (size_t)(bh * NTOK + IMGLEN) * DHEAD;

    float q[32];
    {
        const float* qp = qh + ((size_t)(bh * NTOK + token)) * DHEAD + hb;
#pragma unroll
        for (int e4 = 0; e4 < 8; ++e4) {
            float4 v4 = *(const float4*)(qp + e4 * 4);
            q[e4 * 4] = v4.x; q[e4 * 4 + 1] = v4.y; q[e4 * 4 + 2] = v4.z; q[e4 * 4 + 3] = v4.w;
        }
    }
    float out[32];
#pragma unroll
    for (int e = 0; e < 32; ++e) out[e] = 0.f;
    float m = -1e30f, l = 0.f;

    const int j0 = wave * 64;
#pragma unroll 2
    for (int j = j0; j < j0 + 64; ++j) {
        const float* kr = ktext + j * DHEAD + hb;
        float p0 = 0.f, p1 = 0.f, p2 = 0.f, p3 = 0.f;
#pragma unroll
        for (int e4 = 0; e4 < 8; ++e4) {
            float4 kv = *(const float4*)(kr + e4 * 4);
            p0 += q[e4 * 4] * kv.x;
            p1 += q[e4 * 4 + 1] * kv.y;
            p2 += q[e4 * 4 + 2] * kv.z;
            p3 += q[e4 * 4 + 3] * kv.w;
        }
        float part = (p0 + p1) + (p2 + p3);
        float dot = part + __shfl_xor(part, 32);
        if (dot > m + THR) {
            float cc = __expf(m - dot);
            l *= cc;
#pragma unroll
            for (int e = 0; e < 32; ++e) out[e] *= cc;
            m = dot;
        }
        float p = __expf(dot - m);
        l += p;
        const float* vr = vtext + j * DHEAD + hb;
#pragma unroll
        for (int e4 = 0; e4 < 8; ++e4) {
            float4 vv = *(const float4*)(vr + e4 * 4);
            out[e4 * 4] += p * vv.x;
            out[e4 * 4 + 1] += p * vv.y;
            out[e4 * 4 + 2] += p * vv.z;
            out[e4 * 4 + 3] += p * vv.w;
        }
    }

    // ---- cross-wave merge via LDS ----
    __shared__ float mbuf[2][64];
    __shared__ float lbuf[2][64];
    __shared__ float ob[64][36];
    mbuf[wave][lane] = m;
    lbuf[wave][lane] = l;
    __syncthreads();
    float M = fmaxf(mbuf[0][lane], mbuf[1][lane]);
    float cw = __expf(m - M);
    if (wave == 1) {
#pragma unroll
        for (int e4 = 0; e4 < 8; ++e4) {
            float4 o;
            o.x = cw * out[e4 * 4]; o.y = cw * out[e4 * 4 + 1];
            o.z = cw * out[e4 * 4 + 2]; o.w = cw * out[e4 * 4 + 3];
            *(float4*)&ob[lane][e4 * 4] = o;
        }
        lbuf[1][lane] = cw * l;
    }
    __syncthreads();
    if (wave == 0) {
        float lt = cw * l + lbuf[1][lane];
#pragma unroll
        for (int e = 0; e < 32; ++e) out[e] = cw * out[e] + ob[lane][e];
        if (is_img) {
            float* st = tstate + ((size_t)(bh * IMGLEN + qq)) * STF;
#pragma unroll
            for (int e4 = 0; e4 < 8; ++e4) {
                float4 o;
                o.x = out[e4 * 4]; o.y = out[e4 * 4 + 1];
                o.z = out[e4 * 4 + 2]; o.w = out[e4 * 4 + 3];
                *(float4*)(st + hb + e4 * 4) = o;
            }
            if (h == 0) { st[64] = M; st[65] = lt; }
        } else {
            float inv = 1.f / lt;
            float* dst = attn + ((size_t)(bh * NTOK + qq)) * DHEAD + hb;
#pragma unroll
            for (int e4 = 0; e4 < 8; ++e4) {
                float4 o;
                o.x = out[e4 * 4] * inv; o.y = out[e4 * 4 + 1] * inv;
                o.z = out[e4 * 4 + 2] * inv; o.w = out[e4 * 4 + 3] * inv;
                *(float4*)(dst + e4 * 4) = o;
            }
        }
    }
}

// ---------------- K3: img local 25-slot part + merge with text state ------
// One thread per img query, tap-major scrambled gather, phase-sequenced so
// peak live regs ~100 (q dies before out is loaded) -> no spill.
__global__ __launch_bounds__(64) void attn_img_k(const float* __restrict__ qh,
                                                 const float* __restrict__ kh,
                                                 const float* __restrict__ vh,
                                                 float* __restrict__ attn,
                                                 const float* __restrict__ tstate) {
    const int idx = blockIdx.x * 64 + threadIdx.x;  // 0..16383
    const int bh = idx >> 10;
    const int qq = idx & 1023;
    const int y = qq >> 5, x = qq & 31;
    const float* kimg = kh + (size_t)(bh * NTOK + TEXTN) * DHEAD;
    const float* vimg = vh + (size_t)(bh * NTOK + TEXTN) * DHEAD;
    const float* st = tstate + (size_t)idx * STF;

    float sd[25];
#pragma unroll
    for (int j = 0; j < 25; ++j) sd[j] = 0.f;

    // ---- pass 1: scrambled local dots (q live, dies after) ----
    {
        float q[64];
        const float* qp = qh + ((size_t)(bh * NTOK + TEXTN + qq)) * DHEAD;
#pragma unroll
        for (int dg = 0; dg < 16; ++dg) {
            float4 v4 = *(const float4*)(qp + dg * 4);
            q[dg * 4] = v4.x; q[dg * 4 + 1] = v4.y; q[dg * 4 + 2] = v4.z; q[dg * 4 + 3] = v4.w;
        }
#pragma unroll
        for (int t = 0; t < 25; ++t) {
            const int ny = y + t / 5 - 2;
            const int nx = x + t % 5 - 2;
            if (ny >= 0 && ny < 32 && nx >= 0 && nx < 32) {
                const float* kp = kimg + (size_t)(ny * 32 + nx) * DHEAD;
#pragma unroll
                for (int dg = 0; dg < 16; ++dg) {
                    float4 kv = *(const float4*)(kp + dg * 4);
                    float ke[4] = {kv.x, kv.y, kv.z, kv.w};
#pragma unroll
                    for (int e = 0; e < 4; ++e) {
                        const int d = dg * 4 + e;
                        const int id2 = d * 25 + t;
                        sd[id2 >> 6] += q[id2 & 63] * ke[e];
                    }
                }
            }
        }
    }

    // ---- pass 2: mask + merge with text softmax state ----
    float m = st[64], l = st[65];
    float mloc = -1e30f;
#pragma unroll
    for (int j = 0; j < 25; ++j) {
        const int my = y + j / 5 - 2;
        const int mx = x + j % 5 - 2;
        bool inb = (my >= 0 && my < 32 && mx >= 0 && mx < 32);
        bool keep = inb ? (qq <= my * 32 + mx) : true;
        sd[j] = keep ? sd[j] : -1e30f;
        mloc = fmaxf(mloc, sd[j]);
    }
    float M = fmaxf(m, mloc);
    float cc = __expf(m - M);
    l *= cc;
#pragma unroll
    for (int j = 0; j < 25; ++j) {
        sd[j] = __expf(sd[j] - M);
        l += sd[j];
    }

    // ---- pass 3: load scaled text out ----
    float out[64];
#pragma unroll
    for (int dg = 0; dg < 16; ++dg) {
        float4 o = *(const float4*)(st + dg * 4);
        out[dg * 4] = cc * o.x; out[dg * 4 + 1] = cc * o.y;
        out[dg * 4 + 2] = cc * o.z; out[dg * 4 + 3] = cc * o.w;
    }

    // ---- pass 4: local PV, tap-major ----
#pragma unroll
    for (int t = 0; t < 25; ++t) {
        const int ny = y + t / 5 - 2;
        const int nx = x + t % 5 - 2;
        if (ny >= 0 && ny < 32 && nx >= 0 && nx < 32) {
            const float* vp = vimg + (size_t)(ny * 32 + nx) * DHEAD;
#pragma unroll
            for (int dg = 0; dg < 16; ++dg) {
                float4 vv = *(const float4*)(vp + dg * 4);
                float ve[4] = {vv.x, vv.y, vv.z, vv.w};
#pragma unroll
                for (int e = 0; e < 4; ++e) {
                    const int d = dg * 4 + e;
                    const int id2 = d * 25 + t;
                    out[id2 & 63] += sd[id2 >> 6] * ve[e];
                }
            }
        }
    }

    float inv = 1.f / l;
    float* dst = attn + ((size_t)(bh * NTOK + TEXTN + qq)) * DHEAD;
#pragma unroll
    for (int dg = 0; dg < 16; ++dg) {
        float4 o;
        o.x = out[dg * 4] * inv; o.y = out[dg * 4 + 1] * inv;
        o.z = out[dg * 4 + 2] * inv; o.w = out[dg * 4 + 3] * inv;
        *(float4*)(dst + dg * 4) = o;
    }
}

// ---------------- K4: Y = attn_heads @ w_out + b_out ----------------------
__global__ __launch_bounds__(256) void gemm_out_k(const float* __restrict__ attn,
                                                  const float* __restrict__ W,
                                                  const float* __restrict__ bias,
                                                  float* __restrict__ Y) {
    __shared__ float As[16][68];
    __shared__ float Bs[16][68];
    const int tid = threadIdx.x;
    const int tx = tid & 15, ty = tid >> 4;
    const int row0 = blockIdx.y * 64;
    const int col0 = blockIdx.x * 64;
    float acc[4][4] = {};
    for (int k0 = 0; k0 < DIM; k0 += 16) {
#pragma unroll
        for (int i = 0; i < 4; ++i) {
            int idx = tid + i * 256;
            int mm = idx >> 4, kk = idx & 15;
            int r = row0 + mm, cc = k0 + kk;
            int b_i = r / NTOK, t = r - b_i * NTOK;
            As[kk][mm] = attn[((size_t)(b_i * 8 + (cc >> 6)) * NTOK + t) * DHEAD + (cc & 63)];
            int n2 = idx & 63, kk2 = idx >> 6;
            Bs[kk2][n2] = W[(k0 + kk2) * DIM + col0 + n2];
        }
        __syncthreads();
#pragma unroll
        for (int kk = 0; kk < 16; ++kk) {
            float4 a4 = *(const float4*)&As[kk][ty * 4];
            float4 b4 = *(const float4*)&Bs[kk][tx * 4];
            float a[4] = {a4.x, a4.y, a4.z, a4.w};
            float b[4] = {b4.x, b4.y, b4.z, b4.w};
#pragma unroll
            for (int i = 0; i < 4; ++i)
#pragma unroll
                for (int j2 = 0; j2 < 4; ++j2) acc[i][j2] += a[i] * b[j2];
        }
        __syncthreads();
    }
#pragma unroll
    for (int i = 0; i < 4; ++i) {
        int r = row0 + ty * 4 + i;
#pragma unroll
        for (int j = 0; j < 4; ++j) {
            int cc = col0 + tx * 4 + j;
            Y[(size_t)r * DIM + cc] = acc[i][j] + bias[cc];
        }
    }
}

extern "C" void kernel_launch(void* const* d_in, const int* in_sizes, int n_in,
                              void* d_out, int out_size, void* d_ws, size_t ws_size,
                              hipStream_t stream) {
    const float* x = (const float*)d_in[0];
    const float* w_qkv = (const float*)d_in[1];
    const float* w_out = (const float*)d_in[2];
    const float* b_out = (const float*)d_in[3];
    float* Y = (float*)d_out;
    float* ws = (float*)d_ws;
    float* qh = ws;
    float* kh = ws + (size_t)SEG;
    float* vh = ws + 2 * (size_t)SEG;
    float* attn = ws + 3 * (size_t)SEG;
    float* tstate = ws + 4 * (size_t)SEG;  // 16*1024*68 floats = 4.45 MB

    hipLaunchKernelGGL(gemm_qkv_k, dim3(NQKV / 64, 2304 / 64), dim3(256), 0, stream,
                       x, w_qkv, qh, kh, vh);
    hipLaunchKernelGGL(attn_text_k, dim3(NBH * 36), dim3(128), 0, stream,
                       qh, kh, vh, attn, tstate);
    hipLaunchKernelGGL(attn_img_k, dim3(NBH * IMGLEN / 64), dim3(64), 0, stream,
                       qh, kh, vh, attn, tstate);
    hipLaunchKernelGGL(gemm_out_k, dim3(DIM / 64, 2304 / 64), dim3(256), 0, stream,
                       attn, w_out, b_out, Y);
}

// Round 9
// 199.199 us; speedup vs baseline: 4.5125x; 1.0523x over previous
//
#include <hip/hip_runtime.h>
#include <hip/hip_bf16.h>
#include <math.h>

#define NTOK 1152
#define DIM 512
#define NQKV 1536
#define DHEAD 64
#define NBH 16
#define TEXTN 128
#define IMGLEN 1024
#define SEG (NBH * NTOK * DHEAD)  // 1179648 floats
#define THR 4.0f
#define STF 68  // tstate floats per query: 64 out + m + l + pad

// ---------------- K1: qkv = x @ w_qkv, scatter to head layout, scale q ----
__global__ __launch_bounds__(256) void gemm_qkv_k(const float* __restrict__ X,
                                                  const float* __restrict__ W,
                                                  float* __restrict__ qh,
                                                  float* __restrict__ kh,
                                                  float* __restrict__ vh) {
    __shared__ float As[16][68];
    __shared__ float Bs[16][68];
    const int tid = threadIdx.x;
    const int tx = tid & 15, ty = tid >> 4;
    const int row0 = blockIdx.y * 64;
    const int col0 = blockIdx.x * 64;
    float acc[4][4] = {};
    for (int k0 = 0; k0 < DIM; k0 += 16) {
#pragma unroll
        for (int i = 0; i < 4; ++i) {
            int idx = tid + i * 256;
            int m = idx >> 4, kk = idx & 15;
            As[kk][m] = X[(row0 + m) * DIM + k0 + kk];
            int n2 = idx & 63, kk2 = idx >> 6;
            Bs[kk2][n2] = W[(k0 + kk2) * NQKV + col0 + n2];
        }
        __syncthreads();
#pragma unroll
        for (int kk = 0; kk < 16; ++kk) {
            float4 a4 = *(const float4*)&As[kk][ty * 4];
            float4 b4 = *(const float4*)&Bs[kk][tx * 4];
            float a[4] = {a4.x, a4.y, a4.z, a4.w};
            float b[4] = {b4.x, b4.y, b4.z, b4.w};
#pragma unroll
            for (int i = 0; i < 4; ++i)
#pragma unroll
                for (int j = 0; j < 4; ++j) acc[i][j] += a[i] * b[j];
        }
        __syncthreads();
    }
#pragma unroll
    for (int i = 0; i < 4; ++i) {
        int r = row0 + ty * 4 + i;
        int b_i = r / NTOK, t = r - b_i * NTOK;
#pragma unroll
        for (int j = 0; j < 4; ++j) {
            int c = col0 + tx * 4 + j;
            int which = c >> 9;
            int ci = c & 511;
            int hh = ci >> 6, d = ci & 63;
            float val = acc[i][j];
            if (which == 0) val *= 0.125f;
            float* dst = (which == 0) ? qh : ((which == 1) ? kh : vh);
            dst[((b_i * 8 + hh) * NTOK + t) * DHEAD + d] = val;
        }
    }
}

// ---------------- K2: text-key flash for ALL queries (split-K=2) ----------
__global__ __launch_bounds__(128) void attn_text_k(const float* __restrict__ qh,
                                                   const float* __restrict__ kh,
                                                   const float* __restrict__ vh,
                                                   float* __restrict__ attn,
                                                   float* __restrict__ tstate) {
    const int bh = blockIdx.x / 36;
    const int c = blockIdx.x % 36;
    const bool is_img = (c < 32);
    const int wave = threadIdx.x >> 6;
    const int lane = threadIdx.x & 63;
    const int qsub = lane & 31, h = lane >> 5;
    const int hb = h * 32;
    const int qq = (is_img ? c : (c - 32)) * 32 + qsub;
    const int token = is_img ? (TEXTN + qq) : (IMGLEN + qq);
    const float* ktext = kh + (size_t)(bh * NTOK + IMGLEN) * DHEAD;
    const float* vtext = vh + (size_t)(bh * NTOK + IMGLEN) * DHEAD;

    float q[32];
    {
        const float* qp = qh + ((size_t)(bh * NTOK + token)) * DHEAD + hb;
#pragma unroll
        for (int e4 = 0; e4 < 8; ++e4) {
            float4 v4 = *(const float4*)(qp + e4 * 4);
            q[e4 * 4] = v4.x; q[e4 * 4 + 1] = v4.y; q[e4 * 4 + 2] = v4.z; q[e4 * 4 + 3] = v4.w;
        }
    }
    float out[32];
#pragma unroll
    for (int e = 0; e < 32; ++e) out[e] = 0.f;
    float m = -1e30f, l = 0.f;

    const int j0 = wave * 64;
#pragma unroll 2
    for (int j = j0; j < j0 + 64; ++j) {
        const float* kr = ktext + j * DHEAD + hb;
        float p0 = 0.f, p1 = 0.f, p2 = 0.f, p3 = 0.f;
#pragma unroll
        for (int e4 = 0; e4 < 8; ++e4) {
            float4 kv = *(const float4*)(kr + e4 * 4);
            p0 += q[e4 * 4] * kv.x;
            p1 += q[e4 * 4 + 1] * kv.y;
            p2 += q[e4 * 4 + 2] * kv.z;
            p3 += q[e4 * 4 + 3] * kv.w;
        }
        float part = (p0 + p1) + (p2 + p3);
        float dot = part + __shfl_xor(part, 32);
        if (dot > m + THR) {
            float cc = __expf(m - dot);
            l *= cc;
#pragma unroll
            for (int e = 0; e < 32; ++e) out[e] *= cc;
            m = dot;
        }
        float p = __expf(dot - m);
        l += p;
        const float* vr = vtext + j * DHEAD + hb;
#pragma unroll
        for (int e4 = 0; e4 < 8; ++e4) {
            float4 vv = *(const float4*)(vr + e4 * 4);
            out[e4 * 4] += p * vv.x;
            out[e4 * 4 + 1] += p * vv.y;
            out[e4 * 4 + 2] += p * vv.z;
            out[e4 * 4 + 3] += p * vv.w;
        }
    }

    // ---- cross-wave merge via LDS ----
    __shared__ float mbuf[2][64];
    __shared__ float lbuf[2][64];
    __shared__ float ob[64][36];
    mbuf[wave][lane] = m;
    lbuf[wave][lane] = l;
    __syncthreads();
    float M = fmaxf(mbuf[0][lane], mbuf[1][lane]);
    float cw = __expf(m - M);
    if (wave == 1) {
#pragma unroll
        for (int e4 = 0; e4 < 8; ++e4) {
            float4 o;
            o.x = cw * out[e4 * 4]; o.y = cw * out[e4 * 4 + 1];
            o.z = cw * out[e4 * 4 + 2]; o.w = cw * out[e4 * 4 + 3];
            *(float4*)&ob[lane][e4 * 4] = o;
        }
        lbuf[1][lane] = cw * l;
    }
    __syncthreads();
    if (wave == 0) {
        float lt = cw * l + lbuf[1][lane];
#pragma unroll
        for (int e = 0; e < 32; ++e) out[e] = cw * out[e] + ob[lane][e];
        if (is_img) {
            float* st = tstate + ((size_t)(bh * IMGLEN + qq)) * STF;
#pragma unroll
            for (int e4 = 0; e4 < 8; ++e4) {
                float4 o;
                o.x = out[e4 * 4]; o.y = out[e4 * 4 + 1];
                o.z = out[e4 * 4 + 2]; o.w = out[e4 * 4 + 3];
                *(float4*)(st + hb + e4 * 4) = o;
            }
            if (h == 0) { st[64] = M; st[65] = lt; }
        } else {
            float inv = 1.f / lt;
            float* dst = attn + ((size_t)(bh * NTOK + qq)) * DHEAD + hb;
#pragma unroll
            for (int e4 = 0; e4 < 8; ++e4) {
                float4 o;
                o.x = out[e4 * 4] * inv; o.y = out[e4 * 4 + 1] * inv;
                o.z = out[e4 * 4 + 2] * inv; o.w = out[e4 * 4 + 3] * inv;
                *(float4*)(dst + e4 * 4) = o;
            }
        }
    }
}

// ---------------- K3: img local 25-slot part, wave-split by K/V-channel
// quarter. Block = 256 threads = 4 waves; all waves share 64 queries
// (lane = query). Wave w loads K/V channels [16w,16w+16) only, but needs
// the FULL q[64]: slot flat-index id2 = d*25+t maps to q-element id2&63,
// which spans all 64 channels regardless of d's quarter (round-8 bug).
// All scramble indices compile-time via template W.
template <int W>
__device__ inline void loc_dots(const float* __restrict__ kimg, int y, int x,
                                const float (&q)[64], float (&sd)[25]) {
#pragma unroll
    for (int t = 0; t < 25; ++t) {
        const int ny = y + t / 5 - 2;
        const int nx = x + t % 5 - 2;
        if (ny >= 0 && ny < 32 && nx >= 0 && nx < 32) {
            const float* kp = kimg + (size_t)(ny * 32 + nx) * DHEAD + W * 16;
#pragma unroll
            for (int g = 0; g < 4; ++g) {
                float4 kv = *(const float4*)(kp + g * 4);
                float ke[4] = {kv.x, kv.y, kv.z, kv.w};
#pragma unroll
                for (int e = 0; e < 4; ++e) {
                    const int d = W * 16 + g * 4 + e;
                    const int id2 = d * 25 + t;
                    sd[id2 >> 6] += q[id2 & 63] * ke[e];
                }
            }
        }
    }
}

template <int W>
__device__ inline void loc_pv(const float* __restrict__ vimg, int y, int x,
                              const float (&p)[25], float (&po)[64]) {
#pragma unroll
    for (int t = 0; t < 25; ++t) {
        const int ny = y + t / 5 - 2;
        const int nx = x + t % 5 - 2;
        if (ny >= 0 && ny < 32 && nx >= 0 && nx < 32) {
            const float* vp = vimg + (size_t)(ny * 32 + nx) * DHEAD + W * 16;
#pragma unroll
            for (int g = 0; g < 4; ++g) {
                float4 vv = *(const float4*)(vp + g * 4);
                float ve[4] = {vv.x, vv.y, vv.z, vv.w};
#pragma unroll
                for (int e = 0; e < 4; ++e) {
                    const int d = W * 16 + g * 4 + e;
                    const int id2 = d * 25 + t;
                    po[id2 & 63] += p[id2 >> 6] * ve[e];
                }
            }
        }
    }
}

__global__ __launch_bounds__(256) void attn_img_k(const float* __restrict__ qh,
                                                  const float* __restrict__ kh,
                                                  const float* __restrict__ vh,
                                                  float* __restrict__ attn,
                                                  const float* __restrict__ tstate) {
    __shared__ float sdb[4][64][27];   // 27.6 KB
    __shared__ float pob[2][64][68];   // 34.8 KB
    const int bh = blockIdx.x >> 4;
    const int qtile = (blockIdx.x & 15) << 6;
    const int wave = threadIdx.x >> 6;
    const int lane = threadIdx.x & 63;
    const int qq = qtile + lane;
    const int y = qq >> 5, x = qq & 31;
    const float* kimg = kh + (size_t)(bh * NTOK + TEXTN) * DHEAD;
    const float* vimg = vh + (size_t)(bh * NTOK + TEXTN) * DHEAD;
    const float* st = tstate + ((size_t)(bh * IMGLEN + qq)) * STF;

    // ---- pass 1: partial scrambled dots for this wave's K-channel quarter
    float sd[25];
#pragma unroll
    for (int j = 0; j < 25; ++j) sd[j] = 0.f;
    {
        float q[64];
        const float* qp = qh + ((size_t)(bh * NTOK + TEXTN + qq)) * DHEAD;
#pragma unroll
        for (int g = 0; g < 16; ++g) {
            float4 v4 = *(const float4*)(qp + g * 4);
            q[g * 4] = v4.x; q[g * 4 + 1] = v4.y; q[g * 4 + 2] = v4.z; q[g * 4 + 3] = v4.w;
        }
        if (wave == 0) loc_dots<0>(kimg, y, x, q, sd);
        else if (wave == 1) loc_dots<1>(kimg, y, x, q, sd);
        else if (wave == 2) loc_dots<2>(kimg, y, x, q, sd);
        else loc_dots<3>(kimg, y, x, q, sd);
    }
#pragma unroll
    for (int j = 0; j < 25; ++j) sdb[wave][lane][j] = sd[j];
    __syncthreads();

    // ---- pass 2: sum partials; mask; merge with text softmax state ----
    float p[25];
#pragma unroll
    for (int j = 0; j < 25; ++j)
        p[j] = (sdb[0][lane][j] + sdb[1][lane][j]) + (sdb[2][lane][j] + sdb[3][lane][j]);
    float m = st[64], l = st[65];
    float mloc = -1e30f;
#pragma unroll
    for (int j = 0; j < 25; ++j) {
        const int my = y + j / 5 - 2;
        const int mx = x + j % 5 - 2;
        bool inb = (my >= 0 && my < 32 && mx >= 0 && mx < 32);
        bool keep = inb ? (qq <= my * 32 + mx) : true;
        p[j] = keep ? p[j] : -1e30f;
        mloc = fmaxf(mloc, p[j]);
    }
    const float M = fmaxf(m, mloc);
    const float cc = __expf(m - M);
    l *= cc;
#pragma unroll
    for (int j = 0; j < 25; ++j) {
        p[j] = __expf(p[j] - M);
        l += p[j];
    }
    const float inv = 1.f / l;

    // ---- pass 3: partial PV for this wave's V-channel quarter ----
    float po[64];
#pragma unroll
    for (int o = 0; o < 64; ++o) po[o] = 0.f;
    if (wave == 0) loc_pv<0>(vimg, y, x, p, po);
    else if (wave == 1) loc_pv<1>(vimg, y, x, p, po);
    else if (wave == 2) loc_pv<2>(vimg, y, x, p, po);
    else loc_pv<3>(vimg, y, x, p, po);

    // ---- pass 4: cross-wave PV reduction via LDS (2-step tree) ----
    if (wave < 2) {
#pragma unroll
        for (int o = 0; o < 64; ++o) pob[wave][lane][o] = po[o];
    }
    __syncthreads();
    if (wave >= 2) {
#pragma unroll
        for (int o = 0; o < 64; ++o) pob[wave - 2][lane][o] += po[o];
    }
    __syncthreads();

    // ---- pass 5: finalize this wave's d-quarter of the output ----
    {
        const float* stq = st + wave * 16;
        float* dst = attn + ((size_t)(bh * NTOK + TEXTN + qq)) * DHEAD + wave * 16;
#pragma unroll
        for (int g = 0; g < 4; ++g) {
            float4 tv = *(const float4*)(stq + g * 4);
            float4 a0 = *(const float4*)&pob[0][lane][wave * 16 + g * 4];
            float4 a1 = *(const float4*)&pob[1][lane][wave * 16 + g * 4];
            float4 o;
            o.x = (a0.x + a1.x + cc * tv.x) * inv;
            o.y = (a0.y + a1.y + cc * tv.y) * inv;
            o.z = (a0.z + a1.z + cc * tv.z) * inv;
            o.w = (a0.w + a1.w + cc * tv.w) * inv;
            *(float4*)(dst + g * 4) = o;
        }
    }
}

// ---------------- K4: Y = attn_heads @ w_out + b_out ----------------------
__global__ __launch_bounds__(256) void gemm_out_k(const float* __restrict__ attn,
                                                  const float* __restrict__ W,
                                                  const float* __restrict__ bias,
                                                  float* __restrict__ Y) {
    __shared__ float As[16][68];
    __shared__ float Bs[16][68];
    const int tid = threadIdx.x;
    const int tx = tid & 15, ty = tid >> 4;
    const int row0 = blockIdx.y * 64;
    const int col0 = blockIdx.x * 64;
    float acc[4][4] = {};
    for (int k0 = 0; k0 < DIM; k0 += 16) {
#pragma unroll
        for (int i = 0; i < 4; ++i) {
            int idx = tid + i * 256;
            int mm = idx >> 4, kk = idx & 15;
            int r = row0 + mm, cc = k0 + kk;
            int b_i = r / NTOK, t = r - b_i * NTOK;
            As[kk][mm] = attn[((size_t)(b_i * 8 + (cc >> 6)) * NTOK + t) * DHEAD + (cc & 63)];
            int n2 = idx & 63, kk2 = idx >> 6;
            Bs[kk2][n2] = W[(k0 + kk2) * DIM + col0 + n2];
        }
        __syncthreads();
#pragma unroll
        for (int kk = 0; kk < 16; ++kk) {
            float4 a4 = *(const float4*)&As[kk][ty * 4];
            float4 b4 = *(const float4*)&Bs[kk][tx * 4];
            float a[4] = {a4.x, a4.y, a4.z, a4.w};
            float b[4] = {b4.x, b4.y, b4.z, b4.w};
#pragma unroll
            for (int i = 0; i < 4; ++i)
#pragma unroll
                for (int j2 = 0; j2 < 4; ++j2) acc[i][j2] += a[i] * b[j2];
        }
        __syncthreads();
    }
#pragma unroll
    for (int i = 0; i < 4; ++i) {
        int r = row0 + ty * 4 + i;
#pragma unroll
        for (int j = 0; j < 4; ++j) {
            int cc = col0 + tx * 4 + j;
            Y[(size_t)r * DIM + cc] = acc[i][j] + bias[cc];
        }
    }
}

extern "C" void kernel_launch(void* const* d_in, const int* in_sizes, int n_in,
                              void* d_out, int out_size, void* d_ws, size_t ws_size,
                              hipStream_t stream) {
    const float* x = (const float*)d_in[0];
    const float* w_qkv = (const float*)d_in[1];
    const float* w_out = (const float*)d_in[2];
    const float* b_out = (const float*)d_in[3];
    float* Y = (float*)d_out;
    float* ws = (float*)d_ws;
    float* qh = ws;
    float* kh = ws + (size_t)SEG;
    float* vh = ws + 2 * (size_t)SEG;
    float* attn = ws + 3 * (size_t)SEG;
    float* tstate = ws + 4 * (size_t)SEG;  // 16*1024*68 floats = 4.45 MB

    hipLaunchKernelGGL(gemm_qkv_k, dim3(NQKV / 64, 2304 / 64), dim3(256), 0, stream,
                       x, w_qkv, qh, kh, vh);
    hipLaunchKernelGGL(attn_text_k, dim3(NBH * 36), dim3(128), 0, stream,
                       qh, kh, vh, attn, tstate);
    hipLaunchKernelGGL(attn_img_k, dim3(NBH * 16), dim3(256), 0, stream,
                       qh, kh, vh, attn, tstate);
    hipLaunchKernelGGL(gemm_out_k, dim3(DIM / 64, 2304 / 64), dim3(256), 0, stream,
                       attn, w_out, b_out, Y);
}

// Round 10
// 148.447 us; speedup vs baseline: 6.0552x; 1.3419x over previous
//
#include <hip/hip_runtime.h>
#include <hip/hip_bf16.h>
#include <math.h>

#define NTOK 1152
#define DIM 512
#define NQKV 1536
#define DHEAD 64
#define NBH 16
#define TEXTN 128
#define IMGLEN 1024
#define SEG (NBH * NTOK * DHEAD)  // 1179648
#define THR 4.0f
#define STF 68
#define TSTATE_F (NBH * IMGLEN * STF)
#define LPAD 40  // LDS row stride in bf16 (80B, 16B-aligned, conflict-light)

typedef __attribute__((ext_vector_type(8))) short bf16x8;
typedef __attribute__((ext_vector_type(4))) float f32x4;

__device__ __forceinline__ ushort f2bf(float f) {
    unsigned u = __float_as_uint(f);
    unsigned r = (u + 0x7FFFu + ((u >> 16) & 1u)) >> 16;  // RNE
    return (ushort)r;
}
__device__ __forceinline__ float bf2f(ushort u) {
    return __uint_as_float(((unsigned)u) << 16);
}

// ---------------- P1: x -> x_hi/x_lo bf16 ---------------------------------
__global__ __launch_bounds__(256) void prep_x_k(const float* __restrict__ X,
                                                ushort* __restrict__ xhi,
                                                ushort* __restrict__ xlo) {
    int i = (blockIdx.x * 256 + threadIdx.x) * 4;
    float4 v = *(const float4*)(X + i);
    ushort4 h, l;
    h.x = f2bf(v.x); l.x = f2bf(v.x - bf2f(h.x));
    h.y = f2bf(v.y); l.y = f2bf(v.y - bf2f(h.y));
    h.z = f2bf(v.z); l.z = f2bf(v.z - bf2f(h.z));
    h.w = f2bf(v.w); l.w = f2bf(v.w - bf2f(h.w));
    *(ushort4*)(xhi + i) = h;
    *(ushort4*)(xlo + i) = l;
}

// ---------------- P2: W[K][N] -> Wt_hi/lo[N][K] bf16 ----------------------
__global__ __launch_bounds__(256) void prep_wt_k(const float* __restrict__ W,
                                                 ushort* __restrict__ thi,
                                                 ushort* __restrict__ tlo,
                                                 int K, int N) {
    __shared__ float tile[32][33];
    const int bx = blockIdx.x, by = blockIdx.y;
    const int c = threadIdx.x & 31, r8 = threadIdx.x >> 5;
#pragma unroll
    for (int i = 0; i < 4; ++i) {
        int rr = r8 + i * 8;
        tile[rr][c] = W[(size_t)(by * 32 + rr) * N + bx * 32 + c];
    }
    __syncthreads();
#pragma unroll
    for (int i = 0; i < 4; ++i) {
        int rr = r8 + i * 8;            // n_local
        float v = tile[c][rr];          // W[by*32+c][bx*32+rr]
        size_t o = (size_t)(bx * 32 + rr) * K + by * 32 + c;
        ushort h = f2bf(v);
        thi[o] = h;
        tlo[o] = f2bf(v - bf2f(h));
    }
}

// ---------------- K1: qkv GEMM via split-bf16 MFMA ------------------------
// C = X(2304x512) @ Wqkv(512x1536), tiles 128x64, 4 waves of 64x32.
__global__ __launch_bounds__(256) void gemm_qkv_mfma(const ushort* __restrict__ xhi,
                                                     const ushort* __restrict__ xlo,
                                                     const ushort* __restrict__ wthi,
                                                     const ushort* __restrict__ wtlo,
                                                     float* __restrict__ qh,
                                                     float* __restrict__ kh,
                                                     float* __restrict__ vh) {
    __shared__ __align__(16) ushort Ah[128 * LPAD], Al[128 * LPAD];
    __shared__ __align__(16) ushort Bh[64 * LPAD], Bl[64 * LPAD];
    const int tid = threadIdx.x;
    const int lane = tid & 63;
    const int w = tid >> 6;
    const int wm = w >> 1, wn = w & 1;
    const int row0 = blockIdx.y * 128;
    const int col0 = blockIdx.x * 64;

    f32x4 acc[4][2];
#pragma unroll
    for (int a = 0; a < 4; ++a)
#pragma unroll
        for (int b = 0; b < 2; ++b) acc[a][b] = (f32x4){0.f, 0.f, 0.f, 0.f};

    const int arow = tid >> 1;
    const int akb = (tid & 1) * 16;
    const int brow = tid >> 2;
    const int bkb = (tid & 3) * 8;
    const int kf = (lane >> 4) * 8;
    const int lr = lane & 15;

    for (int k0 = 0; k0 < DIM; k0 += 32) {
        {
            const size_t g = (size_t)(row0 + arow) * DIM + k0 + akb;
            *(bf16x8*)&Ah[arow * LPAD + akb] = *(const bf16x8*)(xhi + g);
            *(bf16x8*)&Ah[arow * LPAD + akb + 8] = *(const bf16x8*)(xhi + g + 8);
            *(bf16x8*)&Al[arow * LPAD + akb] = *(const bf16x8*)(xlo + g);
            *(bf16x8*)&Al[arow * LPAD + akb + 8] = *(const bf16x8*)(xlo + g + 8);
        }
        {
            const size_t g = (size_t)(col0 + brow) * DIM + k0 + bkb;
            *(bf16x8*)&Bh[brow * LPAD + bkb] = *(const bf16x8*)(wthi + g);
            *(bf16x8*)&Bl[brow * LPAD + bkb] = *(const bf16x8*)(wtlo + g);
        }
        __syncthreads();
        bf16x8 ah[4], al[4], bh[2], bl[2];
#pragma unroll
        for (int mi = 0; mi < 4; ++mi) {
            int rr = wm * 64 + mi * 16 + lr;
            ah[mi] = *(const bf16x8*)&Ah[rr * LPAD + kf];
            al[mi] = *(const bf16x8*)&Al[rr * LPAD + kf];
        }
#pragma unroll
        for (int ni = 0; ni < 2; ++ni) {
            int rr = wn * 32 + ni * 16 + lr;
            bh[ni] = *(const bf16x8*)&Bh[rr * LPAD + kf];
            bl[ni] = *(const bf16x8*)&Bl[rr * LPAD + kf];
        }
#pragma unroll
        for (int mi = 0; mi < 4; ++mi)
#pragma unroll
            for (int ni = 0; ni < 2; ++ni) {
                acc[mi][ni] = __builtin_amdgcn_mfma_f32_16x16x32_bf16(ah[mi], bh[ni], acc[mi][ni], 0, 0, 0);
                acc[mi][ni] = __builtin_amdgcn_mfma_f32_16x16x32_bf16(ah[mi], bl[ni], acc[mi][ni], 0, 0, 0);
                acc[mi][ni] = __builtin_amdgcn_mfma_f32_16x16x32_bf16(al[mi], bh[ni], acc[mi][ni], 0, 0, 0);
            }
        __syncthreads();
    }

    // epilogue: whole block lands in ONE (which, head) 64-col chunk
    const int which = col0 >> 9;
    const int hh = (col0 & 511) >> 6;
    const float scale = (which == 0) ? 0.125f : 1.f;
    float* dst = (which == 0) ? qh : ((which == 1) ? kh : vh);
#pragma unroll
    for (int mi = 0; mi < 4; ++mi)
#pragma unroll
        for (int ni = 0; ni < 2; ++ni)
#pragma unroll
            for (int j = 0; j < 4; ++j) {
                int r = row0 + wm * 64 + mi * 16 + (lane >> 4) * 4 + j;
                int b_i = r / NTOK, tok = r - b_i * NTOK;
                int d = wn * 32 + ni * 16 + (lane & 15);
                dst[((size_t)(b_i * 8 + hh) * NTOK + tok) * DHEAD + d] = acc[mi][ni][j] * scale;
            }
}

// ---------------- K2: text-key flash for ALL queries (split-K=2) ----------
__global__ __launch_bounds__(128) void attn_text_k(const float* __restrict__ qh,
                                                   const float* __restrict__ kh,
                                                   const float* __restrict__ vh,
                                                   ushort* __restrict__ ahi,
                                                   ushort* __restrict__ alo,
                                                   float* __restrict__ tstate) {
    const int bh = blockIdx.x / 36;
    const int c = blockIdx.x % 36;
    const bool is_img = (c < 32);
    const int wave = threadIdx.x >> 6;
    const int lane = threadIdx.x & 63;
    const int qsub = lane & 31, h = lane >> 5;
    const int hb = h * 32;
    const int qq = (is_img ? c : (c - 32)) * 32 + qsub;
    const int token = is_img ? (TEXTN + qq) : (IMGLEN + qq);
    const float* ktext = kh + (size_t)(bh * NTOK + IMGLEN) * DHEAD;
    const float* vtext = vh + (size_t)(bh * NTOK + IMGLEN) * DHEAD;

    float q[32];
    {
        const float* qp = qh + ((size_t)(bh * NTOK + token)) * DHEAD + hb;
#pragma unroll
        for (int e4 = 0; e4 < 8; ++e4) {
            float4 v4 = *(const float4*)(qp + e4 * 4);
            q[e4 * 4] = v4.x; q[e4 * 4 + 1] = v4.y; q[e4 * 4 + 2] = v4.z; q[e4 * 4 + 3] = v4.w;
        }
    }
    float out[32];
#pragma unroll
    for (int e = 0; e < 32; ++e) out[e] = 0.f;
    float m = -1e30f, l = 0.f;

    const int j0 = wave * 64;
#pragma unroll 2
    for (int j = j0; j < j0 + 64; ++j) {
        const float* kr = ktext + j * DHEAD + hb;
        float p0 = 0.f, p1 = 0.f, p2 = 0.f, p3 = 0.f;
#pragma unroll
        for (int e4 = 0; e4 < 8; ++e4) {
            float4 kv = *(const float4*)(kr + e4 * 4);
            p0 += q[e4 * 4] * kv.x;
            p1 += q[e4 * 4 + 1] * kv.y;
            p2 += q[e4 * 4 + 2] * kv.z;
            p3 += q[e4 * 4 + 3] * kv.w;
        }
        float part = (p0 + p1) + (p2 + p3);
        float dot = part + __shfl_xor(part, 32);
        if (dot > m + THR) {
            float cc = __expf(m - dot);
            l *= cc;
#pragma unroll
            for (int e = 0; e < 32; ++e) out[e] *= cc;
            m = dot;
        }
        float p = __expf(dot - m);
        l += p;
        const float* vr = vtext + j * DHEAD + hb;
#pragma unroll
        for (int e4 = 0; e4 < 8; ++e4) {
            float4 vv = *(const float4*)(vr + e4 * 4);
            out[e4 * 4] += p * vv.x;
            out[e4 * 4 + 1] += p * vv.y;
            out[e4 * 4 + 2] += p * vv.z;
            out[e4 * 4 + 3] += p * vv.w;
        }
    }

    __shared__ float mbuf[2][64];
    __shared__ float lbuf[2][64];
    __shared__ float ob[64][36];
    mbuf[wave][lane] = m;
    lbuf[wave][lane] = l;
    __syncthreads();
    float M = fmaxf(mbuf[0][lane], mbuf[1][lane]);
    float cw = __expf(m - M);
    if (wave == 1) {
#pragma unroll
        for (int e4 = 0; e4 < 8; ++e4) {
            float4 o;
            o.x = cw * out[e4 * 4]; o.y = cw * out[e4 * 4 + 1];
            o.z = cw * out[e4 * 4 + 2]; o.w = cw * out[e4 * 4 + 3];
            *(float4*)&ob[lane][e4 * 4] = o;
        }
        lbuf[1][lane] = cw * l;
    }
    __syncthreads();
    if (wave == 0) {
        float lt = cw * l + lbuf[1][lane];
#pragma unroll
        for (int e = 0; e < 32; ++e) out[e] = cw * out[e] + ob[lane][e];
        if (is_img) {
            float* st = tstate + ((size_t)(bh * IMGLEN + qq)) * STF;
#pragma unroll
            for (int e4 = 0; e4 < 8; ++e4) {
                float4 o;
                o.x = out[e4 * 4]; o.y = out[e4 * 4 + 1];
                o.z = out[e4 * 4 + 2]; o.w = out[e4 * 4 + 3];
                *(float4*)(st + hb + e4 * 4) = o;
            }
            if (h == 0) { st[64] = M; st[65] = lt; }
        } else {
            float inv = 1.f / lt;
            size_t base = ((size_t)(bh * NTOK + qq)) * DHEAD + hb;
#pragma unroll
            for (int e4 = 0; e4 < 8; ++e4) {
                float v0 = out[e4 * 4] * inv, v1 = out[e4 * 4 + 1] * inv;
                float v2 = out[e4 * 4 + 2] * inv, v3 = out[e4 * 4 + 3] * inv;
                ushort4 oh, ol;
                oh.x = f2bf(v0); ol.x = f2bf(v0 - bf2f(oh.x));
                oh.y = f2bf(v1); ol.y = f2bf(v1 - bf2f(oh.y));
                oh.z = f2bf(v2); ol.z = f2bf(v2 - bf2f(oh.z));
                oh.w = f2bf(v3); ol.w = f2bf(v3 - bf2f(oh.w));
                *(ushort4*)(ahi + base + e4 * 4) = oh;
                *(ushort4*)(alo + base + e4 * 4) = ol;
            }
        }
    }
}

// ---------------- K3: img local 25-slot part, wave-split by K/V quarter ---
template <int W>
__device__ inline void loc_dots(const float* __restrict__ kimg, int y, int x,
                                const float (&q)[64], float (&sd)[25]) {
#pragma unroll
    for (int t = 0; t < 25; ++t) {
        const int ny = y + t / 5 - 2;
        const int nx = x + t % 5 - 2;
        if (ny >= 0 && ny < 32 && nx >= 0 && nx < 32) {
            const float* kp = kimg + (size_t)(ny * 32 + nx) * DHEAD + W * 16;
#pragma unroll
            for (int g = 0; g < 4; ++g) {
                float4 kv = *(const float4*)(kp + g * 4);
                float ke[4] = {kv.x, kv.y, kv.z, kv.w};
#pragma unroll
                for (int e = 0; e < 4; ++e) {
                    const int d = W * 16 + g * 4 + e;
                    const int id2 = d * 25 + t;
                    sd[id2 >> 6] += q[id2 & 63] * ke[e];
                }
            }
        }
    }
}

template <int W>
__device__ inline void loc_pv(const float* __restrict__ vimg, int y, int x,
                              const float (&p)[25], float (&po)[64]) {
#pragma unroll
    for (int t = 0; t < 25; ++t) {
        const int ny = y + t / 5 - 2;
        const int nx = x + t % 5 - 2;
        if (ny >= 0 && ny < 32 && nx >= 0 && nx < 32) {
            const float* vp = vimg + (size_t)(ny * 32 + nx) * DHEAD + W * 16;
#pragma unroll
            for (int g = 0; g < 4; ++g) {
                float4 vv = *(const float4*)(vp + g * 4);
                float ve[4] = {vv.x, vv.y, vv.z, vv.w};
#pragma unroll
                for (int e = 0; e < 4; ++e) {
                    const int d = W * 16 + g * 4 + e;
                    const int id2 = d * 25 + t;
                    po[id2 & 63] += p[id2 >> 6] * ve[e];
                }
            }
        }
    }
}

__global__ __launch_bounds__(256) void attn_img_k(const float* __restrict__ qh,
                                                  const float* __restrict__ kh,
                                                  const float* __restrict__ vh,
                                                  ushort* __restrict__ ahi,
                                                  ushort* __restrict__ alo,
                                                  const float* __restrict__ tstate) {
    __shared__ float sdb[4][64][27];
    __shared__ float pob[2][64][68];
    const int bh = blockIdx.x >> 4;
    const int qtile = (blockIdx.x & 15) << 6;
    const int wave = threadIdx.x >> 6;
    const int lane = threadIdx.x & 63;
    const int qq = qtile + lane;
    const int y = qq >> 5, x = qq & 31;
    const float* kimg = kh + (size_t)(bh * NTOK + TEXTN) * DHEAD;
    const float* vimg = vh + (size_t)(bh * NTOK + TEXTN) * DHEAD;
    const float* st = tstate + ((size_t)(bh * IMGLEN + qq)) * STF;

    float sd[25];
#pragma unroll
    for (int j = 0; j < 25; ++j) sd[j] = 0.f;
    {
        float q[64];
        const float* qp = qh + ((size_t)(bh * NTOK + TEXTN + qq)) * DHEAD;
#pragma unroll
        for (int g = 0; g < 16; ++g) {
            float4 v4 = *(const float4*)(qp + g * 4);
            q[g * 4] = v4.x; q[g * 4 + 1] = v4.y; q[g * 4 + 2] = v4.z; q[g * 4 + 3] = v4.w;
        }
        if (wave == 0) loc_dots<0>(kimg, y, x, q, sd);
        else if (wave == 1) loc_dots<1>(kimg, y, x, q, sd);
        else if (wave == 2) loc_dots<2>(kimg, y, x, q, sd);
        else loc_dots<3>(kimg, y, x, q, sd);
    }
#pragma unroll
    for (int j = 0; j < 25; ++j) sdb[wave][lane][j] = sd[j];
    __syncthreads();

    float p[25];
#pragma unroll
    for (int j = 0; j < 25; ++j)
        p[j] = (sdb[0][lane][j] + sdb[1][lane][j]) + (sdb[2][lane][j] + sdb[3][lane][j]);
    float m = st[64], l = st[65];
    float mloc = -1e30f;
#pragma unroll
    for (int j = 0; j < 25; ++j) {
        const int my = y + j / 5 - 2;
        const int mx = x + j % 5 - 2;
        bool inb = (my >= 0 && my < 32 && mx >= 0 && mx < 32);
        bool keep = inb ? (qq <= my * 32 + mx) : true;
        p[j] = keep ? p[j] : -1e30f;
        mloc = fmaxf(mloc, p[j]);
    }
    const float M = fmaxf(m, mloc);
    const float cc = __expf(m - M);
    l *= cc;
#pragma unroll
    for (int j = 0; j < 25; ++j) {
        p[j] = __expf(p[j] - M);
        l += p[j];
    }
    const float inv = 1.f / l;

    float po[64];
#pragma unroll
    for (int o = 0; o < 64; ++o) po[o] = 0.f;
    if (wave == 0) loc_pv<0>(vimg, y, x, p, po);
    else if (wave == 1) loc_pv<1>(vimg, y, x, p, po);
    else if (wave == 2) loc_pv<2>(vimg, y, x, p, po);
    else loc_pv<3>(vimg, y, x, p, po);

    if (wave < 2) {
#pragma unroll
        for (int o = 0; o < 64; ++o) pob[wave][lane][o] = po[o];
    }
    __syncthreads();
    if (wave >= 2) {
#pragma unroll
        for (int o = 0; o < 64; ++o) pob[wave - 2][lane][o] += po[o];
    }
    __syncthreads();

    {
        const float* stq = st + wave * 16;
        size_t base = ((size_t)(bh * NTOK + TEXTN + qq)) * DHEAD + wave * 16;
#pragma unroll
        for (int g = 0; g < 4; ++g) {
            float4 tv = *(const float4*)(stq + g * 4);
            float4 a0 = *(const float4*)&pob[0][lane][wave * 16 + g * 4];
            float4 a1 = *(const float4*)&pob[1][lane][wave * 16 + g * 4];
            float v0 = (a0.x + a1.x + cc * tv.x) * inv;
            float v1 = (a0.y + a1.y + cc * tv.y) * inv;
            float v2 = (a0.z + a1.z + cc * tv.z) * inv;
            float v3 = (a0.w + a1.w + cc * tv.w) * inv;
            ushort4 oh, ol;
            oh.x = f2bf(v0); ol.x = f2bf(v0 - bf2f(oh.x));
            oh.y = f2bf(v1); ol.y = f2bf(v1 - bf2f(oh.y));
            oh.z = f2bf(v2); ol.z = f2bf(v2 - bf2f(oh.z));
            oh.w = f2bf(v3); ol.w = f2bf(v3 - bf2f(oh.w));
            *(ushort4*)(ahi + base + g * 4) = oh;
            *(ushort4*)(alo + base + g * 4) = ol;
        }
    }
}

// ---------------- K4: out GEMM via split-bf16 MFMA ------------------------
// Y = attn(2304x512, head-major gather) @ Wout(512x512) + bias.
__global__ __launch_bounds__(256) void gemm_out_mfma(const ushort* __restrict__ ahi,
                                                     const ushort* __restrict__ alo,
                                                     const ushort* __restrict__ wthi,
                                                     const ushort* __restrict__ wtlo,
                                                     const float* __restrict__ bias,
                                                     float* __restrict__ Y) {
    __shared__ __align__(16) ushort Ah[128 * LPAD], Al[128 * LPAD];
    __shared__ __align__(16) ushort Bh[64 * LPAD], Bl[64 * LPAD];
    const int tid = threadIdx.x;
    const int lane = tid & 63;
    const int w = tid >> 6;
    const int wm = w >> 1, wn = w & 1;
    const int row0 = blockIdx.y * 128;
    const int col0 = blockIdx.x * 64;

    f32x4 acc[4][2];
#pragma unroll
    for (int a = 0; a < 4; ++a)
#pragma unroll
        for (int b = 0; b < 2; ++b) acc[a][b] = (f32x4){0.f, 0.f, 0.f, 0.f};

    const int arow = tid >> 1;
    const int akb = (tid & 1) * 16;
    const int brow = tid >> 2;
    const int bkb = (tid & 3) * 8;
    const int kf = (lane >> 4) * 8;
    const int lr = lane & 15;

    const int ar = row0 + arow;
    const int a_bi = ar / NTOK;
    const int a_tok = ar - a_bi * NTOK;

    for (int k0 = 0; k0 < DIM; k0 += 32) {
        {
            const int kg = k0 + akb;
            const int hh = kg >> 6, d0 = kg & 63;
            const size_t g = ((size_t)(a_bi * 8 + hh) * NTOK + a_tok) * DHEAD + d0;
            *(bf16x8*)&Ah[arow * LPAD + akb] = *(const bf16x8*)(ahi + g);
            *(bf16x8*)&Ah[arow * LPAD + akb + 8] = *(const bf16x8*)(ahi + g + 8);
            *(bf16x8*)&Al[arow * LPAD + akb] = *(const bf16x8*)(alo + g);
            *(bf16x8*)&Al[arow * LPAD + akb + 8] = *(const bf16x8*)(alo + g + 8);
        }
        {
            const size_t g = (size_t)(col0 + brow) * DIM + k0 + bkb;
            *(bf16x8*)&Bh[brow * LPAD + bkb] = *(const bf16x8*)(wthi + g);
            *(bf16x8*)&Bl[brow * LPAD + bkb] = *(const bf16x8*)(wtlo + g);
        }
        __syncthreads();
        bf16x8 ah[4], al[4], bh[2], bl[2];
#pragma unroll
        for (int mi = 0; mi < 4; ++mi) {
            int rr = wm * 64 + mi * 16 + lr;
            ah[mi] = *(const bf16x8*)&Ah[rr * LPAD + kf];
            al[mi] = *(const bf16x8*)&Al[rr * LPAD + kf];
        }
#pragma unroll
        for (int ni = 0; ni < 2; ++ni) {
            int rr = wn * 32 + ni * 16 + lr;
            bh[ni] = *(const bf16x8*)&Bh[rr * LPAD + kf];
            bl[ni] = *(const bf16x8*)&Bl[rr * LPAD + kf];
        }
#pragma unroll
        for (int mi = 0; mi < 4; ++mi)
#pragma unroll
            for (int ni = 0; ni < 2; ++ni) {
                acc[mi][ni] = __builtin_amdgcn_mfma_f32_16x16x32_bf16(ah[mi], bh[ni], acc[mi][ni], 0, 0, 0);
                acc[mi][ni] = __builtin_amdgcn_mfma_f32_16x16x32_bf16(ah[mi], bl[ni], acc[mi][ni], 0, 0, 0);
                acc[mi][ni] = __builtin_amdgcn_mfma_f32_16x16x32_bf16(al[mi], bh[ni], acc[mi][ni], 0, 0, 0);
            }
        __syncthreads();
    }

#pragma unroll
    for (int mi = 0; mi < 4; ++mi)
#pragma unroll
        for (int ni = 0; ni < 2; ++ni) {
            int cidx = col0 + wn * 32 + ni * 16 + (lane & 15);
            float bv = bias[cidx];
#pragma unroll
            for (int j = 0; j < 4; ++j) {
                int r = row0 + wm * 64 + mi * 16 + (lane >> 4) * 4 + j;
                Y[(size_t)r * DIM + cidx] = acc[mi][ni][j] + bv;
            }
        }
}

extern "C" void kernel_launch(void* const* d_in, const int* in_sizes, int n_in,
                              void* d_out, int out_size, void* d_ws, size_t ws_size,
                              hipStream_t stream) {
    const float* x = (const float*)d_in[0];
    const float* w_qkv = (const float*)d_in[1];
    const float* w_out = (const float*)d_in[2];
    const float* b_out = (const float*)d_in[3];
    float* Y = (float*)d_out;
    float* ws = (float*)d_ws;
    float* qh = ws;
    float* kh = ws + (size_t)SEG;
    float* vh = ws + 2 * (size_t)SEG;
    float* tstate = ws + 3 * (size_t)SEG;
    ushort* xhi = (ushort*)(ws + 3 * (size_t)SEG + TSTATE_F);
    ushort* xlo = xhi + (size_t)SEG;
    ushort* ahi = xhi;  // alias: x dead after gemm_qkv; attn written after
    ushort* alo = xlo;
    ushort* wqthi = xlo + (size_t)SEG;
    ushort* wqtlo = wqthi + (size_t)DIM * NQKV;
    ushort* wothi = wqtlo + (size_t)DIM * NQKV;
    ushort* wotlo = wothi + (size_t)DIM * DIM;

    hipLaunchKernelGGL(prep_x_k, dim3(SEG / 1024), dim3(256), 0, stream, x, xhi, xlo);
    hipLaunchKernelGGL(prep_wt_k, dim3(NQKV / 32, DIM / 32), dim3(256), 0, stream,
                       w_qkv, wqthi, wqtlo, DIM, NQKV);
    hipLaunchKernelGGL(prep_wt_k, dim3(DIM / 32, DIM / 32), dim3(256), 0, stream,
                       w_out, wothi, wotlo, DIM, DIM);
    hipLaunchKernelGGL(gemm_qkv_mfma, dim3(NQKV / 64, 2304 / 128), dim3(256), 0, stream,
                       xhi, xlo, wqthi, wqtlo, qh, kh, vh);
    hipLaunchKernelGGL(attn_text_k, dim3(NBH * 36), dim3(128), 0, stream,
                       qh, kh, vh, ahi, alo, tstate);
    hipLaunchKernelGGL(attn_img_k, dim3(NBH * 16), dim3(256), 0, stream,
                       qh, kh, vh, ahi, alo, tstate);
    hipLaunchKernelGGL(gemm_out_mfma, dim3(DIM / 64, 2304 / 128), dim3(256), 0, stream,
                       ahi, alo, wothi, wotlo, b_out, Y);
}

// Round 11
// 147.241 us; speedup vs baseline: 6.1049x; 1.0082x over previous
//
#include <hip/hip_runtime.h>
#include <hip/hip_bf16.h>
#include <math.h>

#define NTOK 1152
#define DIM 512
#define NQKV 1536
#define DHEAD 64
#define NBH 16
#define TEXTN 128
#define IMGLEN 1024
#define SEG (NBH * NTOK * DHEAD)  // 1179648
#define THR 4.0f
#define STF 68
#define TSTATE_F (NBH * IMGLEN * STF)
#define LPAD 40  // LDS row stride in bf16 (80B, 16B-aligned, conflict-light)

typedef __attribute__((ext_vector_type(8))) short bf16x8;
typedef __attribute__((ext_vector_type(4))) float f32x4;

__device__ __forceinline__ ushort f2bf(float f) {
    unsigned u = __float_as_uint(f);
    unsigned r = (u + 0x7FFFu + ((u >> 16) & 1u)) >> 16;  // RNE
    return (ushort)r;
}
__device__ __forceinline__ float bf2f(ushort u) {
    return __uint_as_float(((unsigned)u) << 16);
}

// ---------------- P1: x -> x_hi/x_lo bf16 ---------------------------------
__global__ __launch_bounds__(256) void prep_x_k(const float* __restrict__ X,
                                                ushort* __restrict__ xhi,
                                                ushort* __restrict__ xlo) {
    int i = (blockIdx.x * 256 + threadIdx.x) * 4;
    float4 v = *(const float4*)(X + i);
    ushort4 h, l;
    h.x = f2bf(v.x); l.x = f2bf(v.x - bf2f(h.x));
    h.y = f2bf(v.y); l.y = f2bf(v.y - bf2f(h.y));
    h.z = f2bf(v.z); l.z = f2bf(v.z - bf2f(h.z));
    h.w = f2bf(v.w); l.w = f2bf(v.w - bf2f(h.w));
    *(ushort4*)(xhi + i) = h;
    *(ushort4*)(xlo + i) = l;
}

// ---------------- P2: W[K][N] -> Wt_hi/lo[N][K] bf16 ----------------------
__global__ __launch_bounds__(256) void prep_wt_k(const float* __restrict__ W,
                                                 ushort* __restrict__ thi,
                                                 ushort* __restrict__ tlo,
                                                 int K, int N) {
    __shared__ float tile[32][33];
    const int bx = blockIdx.x, by = blockIdx.y;
    const int c = threadIdx.x & 31, r8 = threadIdx.x >> 5;
#pragma unroll
    for (int i = 0; i < 4; ++i) {
        int rr = r8 + i * 8;
        tile[rr][c] = W[(size_t)(by * 32 + rr) * N + bx * 32 + c];
    }
    __syncthreads();
#pragma unroll
    for (int i = 0; i < 4; ++i) {
        int rr = r8 + i * 8;            // n_local
        float v = tile[c][rr];          // W[by*32+c][bx*32+rr]
        size_t o = (size_t)(bx * 32 + rr) * K + by * 32 + c;
        ushort h = f2bf(v);
        thi[o] = h;
        tlo[o] = f2bf(v - bf2f(h));
    }
}

// ---------------- K1: qkv GEMM via split-bf16 MFMA ------------------------
__global__ __launch_bounds__(256) void gemm_qkv_mfma(const ushort* __restrict__ xhi,
                                                     const ushort* __restrict__ xlo,
                                                     const ushort* __restrict__ wthi,
                                                     const ushort* __restrict__ wtlo,
                                                     float* __restrict__ qh,
                                                     float* __restrict__ kh,
                                                     float* __restrict__ vh) {
    __shared__ __align__(16) ushort Ah[128 * LPAD], Al[128 * LPAD];
    __shared__ __align__(16) ushort Bh[64 * LPAD], Bl[64 * LPAD];
    const int tid = threadIdx.x;
    const int lane = tid & 63;
    const int w = tid >> 6;
    const int wm = w >> 1, wn = w & 1;
    const int row0 = blockIdx.y * 128;
    const int col0 = blockIdx.x * 64;

    f32x4 acc[4][2];
#pragma unroll
    for (int a = 0; a < 4; ++a)
#pragma unroll
        for (int b = 0; b < 2; ++b) acc[a][b] = (f32x4){0.f, 0.f, 0.f, 0.f};

    const int arow = tid >> 1;
    const int akb = (tid & 1) * 16;
    const int brow = tid >> 2;
    const int bkb = (tid & 3) * 8;
    const int kf = (lane >> 4) * 8;
    const int lr = lane & 15;

    for (int k0 = 0; k0 < DIM; k0 += 32) {
        {
            const size_t g = (size_t)(row0 + arow) * DIM + k0 + akb;
            *(bf16x8*)&Ah[arow * LPAD + akb] = *(const bf16x8*)(xhi + g);
            *(bf16x8*)&Ah[arow * LPAD + akb + 8] = *(const bf16x8*)(xhi + g + 8);
            *(bf16x8*)&Al[arow * LPAD + akb] = *(const bf16x8*)(xlo + g);
            *(bf16x8*)&Al[arow * LPAD + akb + 8] = *(const bf16x8*)(xlo + g + 8);
        }
        {
            const size_t g = (size_t)(col0 + brow) * DIM + k0 + bkb;
            *(bf16x8*)&Bh[brow * LPAD + bkb] = *(const bf16x8*)(wthi + g);
            *(bf16x8*)&Bl[brow * LPAD + bkb] = *(const bf16x8*)(wtlo + g);
        }
        __syncthreads();
        bf16x8 ah[4], al[4], bh[2], bl[2];
#pragma unroll
        for (int mi = 0; mi < 4; ++mi) {
            int rr = wm * 64 + mi * 16 + lr;
            ah[mi] = *(const bf16x8*)&Ah[rr * LPAD + kf];
            al[mi] = *(const bf16x8*)&Al[rr * LPAD + kf];
        }
#pragma unroll
        for (int ni = 0; ni < 2; ++ni) {
            int rr = wn * 32 + ni * 16 + lr;
            bh[ni] = *(const bf16x8*)&Bh[rr * LPAD + kf];
            bl[ni] = *(const bf16x8*)&Bl[rr * LPAD + kf];
        }
#pragma unroll
        for (int mi = 0; mi < 4; ++mi)
#pragma unroll
            for (int ni = 0; ni < 2; ++ni) {
                acc[mi][ni] = __builtin_amdgcn_mfma_f32_16x16x32_bf16(ah[mi], bh[ni], acc[mi][ni], 0, 0, 0);
                acc[mi][ni] = __builtin_amdgcn_mfma_f32_16x16x32_bf16(ah[mi], bl[ni], acc[mi][ni], 0, 0, 0);
                acc[mi][ni] = __builtin_amdgcn_mfma_f32_16x16x32_bf16(al[mi], bh[ni], acc[mi][ni], 0, 0, 0);
            }
        __syncthreads();
    }

    const int which = col0 >> 9;
    const int hh = (col0 & 511) >> 6;
    const float scale = (which == 0) ? 0.125f : 1.f;
    float* dst = (which == 0) ? qh : ((which == 1) ? kh : vh);
#pragma unroll
    for (int mi = 0; mi < 4; ++mi)
#pragma unroll
        for (int ni = 0; ni < 2; ++ni)
#pragma unroll
            for (int j = 0; j < 4; ++j) {
                int r = row0 + wm * 64 + mi * 16 + (lane >> 4) * 4 + j;
                int b_i = r / NTOK, tok = r - b_i * NTOK;
                int d = wn * 32 + ni * 16 + (lane & 15);
                dst[((size_t)(b_i * 8 + hh) * NTOK + tok) * DHEAD + d] = acc[mi][ni][j] * scale;
            }
}

// ---------------- K2: text-key flash for ALL queries (4-way key split) ----
// Block = 256 threads = 4 waves; wave w handles keys [32w, 32w+32).
// Lane = qsub(0..31) + 32*h (d-half). 2-key ILP in the loop body.
__global__ __launch_bounds__(256) void attn_text_k(const float* __restrict__ qh,
                                                   const float* __restrict__ kh,
                                                   const float* __restrict__ vh,
                                                   ushort* __restrict__ ahi,
                                                   ushort* __restrict__ alo,
                                                   float* __restrict__ tstate) {
    const int bh = blockIdx.x / 36;
    const int c = blockIdx.x % 36;
    const bool is_img = (c < 32);
    const int wave = threadIdx.x >> 6;
    const int lane = threadIdx.x & 63;
    const int qsub = lane & 31, h = lane >> 5;
    const int hb = h * 32;
    const int qq = (is_img ? c : (c - 32)) * 32 + qsub;
    const int token = is_img ? (TEXTN + qq) : (IMGLEN + qq);
    const float* ktext = kh + (size_t)(bh * NTOK + IMGLEN) * DHEAD;
    const float* vtext = vh + (size_t)(bh * NTOK + IMGLEN) * DHEAD;

    float q[32];
    {
        const float* qp = qh + ((size_t)(bh * NTOK + token)) * DHEAD + hb;
#pragma unroll
        for (int e4 = 0; e4 < 8; ++e4) {
            float4 v4 = *(const float4*)(qp + e4 * 4);
            q[e4 * 4] = v4.x; q[e4 * 4 + 1] = v4.y; q[e4 * 4 + 2] = v4.z; q[e4 * 4 + 3] = v4.w;
        }
    }
    float out[32];
#pragma unroll
    for (int e = 0; e < 32; ++e) out[e] = 0.f;
    float m = -1e30f, l = 0.f;

    const int j0 = wave * 32;
#pragma unroll 2
    for (int jj = 0; jj < 32; jj += 2) {
        const int ja = j0 + jj, jb = ja + 1;
        const float* kra = ktext + ja * DHEAD + hb;
        const float* krb = ktext + jb * DHEAD + hb;
        float a0 = 0.f, a1 = 0.f, b0 = 0.f, b1 = 0.f;
#pragma unroll
        for (int e4 = 0; e4 < 8; ++e4) {
            float4 ka = *(const float4*)(kra + e4 * 4);
            float4 kb = *(const float4*)(krb + e4 * 4);
            a0 += q[e4 * 4] * ka.x + q[e4 * 4 + 1] * ka.y;
            a1 += q[e4 * 4 + 2] * ka.z + q[e4 * 4 + 3] * ka.w;
            b0 += q[e4 * 4] * kb.x + q[e4 * 4 + 1] * kb.y;
            b1 += q[e4 * 4 + 2] * kb.z + q[e4 * 4 + 3] * kb.w;
        }
        float parta = a0 + a1, partb = b0 + b1;
        float dota = parta + __shfl_xor(parta, 32);
        float dotb = partb + __shfl_xor(partb, 32);
        float d2 = fmaxf(dota, dotb);
        if (d2 > m + THR) {
            float cc = __expf(m - d2);
            l *= cc;
#pragma unroll
            for (int e = 0; e < 32; ++e) out[e] *= cc;
            m = d2;
        }
        float pa = __expf(dota - m);
        float pb = __expf(dotb - m);
        l += pa + pb;
        const float* vra = vtext + ja * DHEAD + hb;
        const float* vrb = vtext + jb * DHEAD + hb;
#pragma unroll
        for (int e4 = 0; e4 < 8; ++e4) {
            float4 va = *(const float4*)(vra + e4 * 4);
            float4 vb = *(const float4*)(vrb + e4 * 4);
            out[e4 * 4] += pa * va.x + pb * vb.x;
            out[e4 * 4 + 1] += pa * va.y + pb * vb.y;
            out[e4 * 4 + 2] += pa * va.z + pb * vb.z;
            out[e4 * 4 + 3] += pa * va.w + pb * vb.w;
        }
    }

    // ---- 4-way cross-wave merge via LDS ----
    __shared__ float mbuf[4][64];
    __shared__ float lbuf[4][64];
    __shared__ float ob[4][64][33];
    mbuf[wave][lane] = m;
    __syncthreads();
    float M = fmaxf(fmaxf(mbuf[0][lane], mbuf[1][lane]),
                    fmaxf(mbuf[2][lane], mbuf[3][lane]));
    float cw = __expf(m - M);
    lbuf[wave][lane] = cw * l;
#pragma unroll
    for (int e4 = 0; e4 < 8; ++e4) {
        float4 o;
        o.x = cw * out[e4 * 4]; o.y = cw * out[e4 * 4 + 1];
        o.z = cw * out[e4 * 4 + 2]; o.w = cw * out[e4 * 4 + 3];
        *(float4*)&ob[wave][lane][e4 * 4] = o;
    }
    __syncthreads();
    if (wave == 0) {
        float lt = (lbuf[0][lane] + lbuf[1][lane]) + (lbuf[2][lane] + lbuf[3][lane]);
#pragma unroll
        for (int e = 0; e < 32; ++e)
            out[e] = (ob[0][lane][e] + ob[1][lane][e]) + (ob[2][lane][e] + ob[3][lane][e]);
        if (is_img) {
            float* st = tstate + ((size_t)(bh * IMGLEN + qq)) * STF;
#pragma unroll
            for (int e4 = 0; e4 < 8; ++e4) {
                float4 o;
                o.x = out[e4 * 4]; o.y = out[e4 * 4 + 1];
                o.z = out[e4 * 4 + 2]; o.w = out[e4 * 4 + 3];
                *(float4*)(st + hb + e4 * 4) = o;
            }
            if (h == 0) { st[64] = M; st[65] = lt; }
        } else {
            float inv = 1.f / lt;
            size_t base = ((size_t)(bh * NTOK + qq)) * DHEAD + hb;
#pragma unroll
            for (int e4 = 0; e4 < 8; ++e4) {
                float v0 = out[e4 * 4] * inv, v1 = out[e4 * 4 + 1] * inv;
                float v2 = out[e4 * 4 + 2] * inv, v3 = out[e4 * 4 + 3] * inv;
                ushort4 oh, ol;
                oh.x = f2bf(v0); ol.x = f2bf(v0 - bf2f(oh.x));
                oh.y = f2bf(v1); ol.y = f2bf(v1 - bf2f(oh.y));
                oh.z = f2bf(v2); ol.z = f2bf(v2 - bf2f(oh.z));
                oh.w = f2bf(v3); ol.w = f2bf(v3 - bf2f(oh.w));
                *(ushort4*)(ahi + base + e4 * 4) = oh;
                *(ushort4*)(alo + base + e4 * 4) = ol;
            }
        }
    }
}

// ---------------- K3: img local 25-slot part, wave-split by K/V quarter ---
template <int W>
__device__ inline void loc_dots(const float* __restrict__ kimg, int y, int x,
                                const float (&q)[64], float (&sd)[25]) {
#pragma unroll
    for (int t = 0; t < 25; ++t) {
        const int ny = y + t / 5 - 2;
        const int nx = x + t % 5 - 2;
        if (ny >= 0 && ny < 32 && nx >= 0 && nx < 32) {
            const float* kp = kimg + (size_t)(ny * 32 + nx) * DHEAD + W * 16;
#pragma unroll
            for (int g = 0; g < 4; ++g) {
                float4 kv = *(const float4*)(kp + g * 4);
                float ke[4] = {kv.x, kv.y, kv.z, kv.w};
#pragma unroll
                for (int e = 0; e < 4; ++e) {
                    const int d = W * 16 + g * 4 + e;
                    const int id2 = d * 25 + t;
                    sd[id2 >> 6] += q[id2 & 63] * ke[e];
                }
            }
        }
    }
}

template <int W>
__device__ inline void loc_pv(const float* __restrict__ vimg, int y, int x,
                              const float (&p)[25], float (&po)[64]) {
#pragma unroll
    for (int t = 0; t < 25; ++t) {
        const int ny = y + t / 5 - 2;
        const int nx = x + t % 5 - 2;
        if (ny >= 0 && ny < 32 && nx >= 0 && nx < 32) {
            const float* vp = vimg + (size_t)(ny * 32 + nx) * DHEAD + W * 16;
#pragma unroll
            for (int g = 0; g < 4; ++g) {
                float4 vv = *(const float4*)(vp + g * 4);
                float ve[4] = {vv.x, vv.y, vv.z, vv.w};
#pragma unroll
                for (int e = 0; e < 4; ++e) {
                    const int d = W * 16 + g * 4 + e;
                    const int id2 = d * 25 + t;
                    po[id2 & 63] += p[id2 >> 6] * ve[e];
                }
            }
        }
    }
}

__global__ __launch_bounds__(256) void attn_img_k(const float* __restrict__ qh,
                                                  const float* __restrict__ kh,
                                                  const float* __restrict__ vh,
                                                  ushort* __restrict__ ahi,
                                                  ushort* __restrict__ alo,
                                                  const float* __restrict__ tstate) {
    __shared__ float sdb[4][64][27];
    __shared__ float pob[2][64][68];
    const int bh = blockIdx.x >> 4;
    const int qtile = (blockIdx.x & 15) << 6;
    const int wave = threadIdx.x >> 6;
    const int lane = threadIdx.x & 63;
    const int qq = qtile + lane;
    const int y = qq >> 5, x = qq & 31;
    const float* kimg = kh + (size_t)(bh * NTOK + TEXTN) * DHEAD;
    const float* vimg = vh + (size_t)(bh * NTOK + TEXTN) * DHEAD;
    const float* st = tstate + ((size_t)(bh * IMGLEN + qq)) * STF;

    float sd[25];
#pragma unroll
    for (int j = 0; j < 25; ++j) sd[j] = 0.f;
    {
        float q[64];
        const float* qp = qh + ((size_t)(bh * NTOK + TEXTN + qq)) * DHEAD;
#pragma unroll
        for (int g = 0; g < 16; ++g) {
            float4 v4 = *(const float4*)(qp + g * 4);
            q[g * 4] = v4.x; q[g * 4 + 1] = v4.y; q[g * 4 + 2] = v4.z; q[g * 4 + 3] = v4.w;
        }
        if (wave == 0) loc_dots<0>(kimg, y, x, q, sd);
        else if (wave == 1) loc_dots<1>(kimg, y, x, q, sd);
        else if (wave == 2) loc_dots<2>(kimg, y, x, q, sd);
        else loc_dots<3>(kimg, y, x, q, sd);
    }
#pragma unroll
    for (int j = 0; j < 25; ++j) sdb[wave][lane][j] = sd[j];
    __syncthreads();

    float p[25];
#pragma unroll
    for (int j = 0; j < 25; ++j)
        p[j] = (sdb[0][lane][j] + sdb[1][lane][j]) + (sdb[2][lane][j] + sdb[3][lane][j]);
    float m = st[64], l = st[65];
    float mloc = -1e30f;
#pragma unroll
    for (int j = 0; j < 25; ++j) {
        const int my = y + j / 5 - 2;
        const int mx = x + j % 5 - 2;
        bool inb = (my >= 0 && my < 32 && mx >= 0 && mx < 32);
        bool keep = inb ? (qq <= my * 32 + mx) : true;
        p[j] = keep ? p[j] : -1e30f;
        mloc = fmaxf(mloc, p[j]);
    }
    const float M = fmaxf(m, mloc);
    const float cc = __expf(m - M);
    l *= cc;
#pragma unroll
    for (int j = 0; j < 25; ++j) {
        p[j] = __expf(p[j] - M);
        l += p[j];
    }
    const float inv = 1.f / l;

    float po[64];
#pragma unroll
    for (int o = 0; o < 64; ++o) po[o] = 0.f;
    if (wave == 0) loc_pv<0>(vimg, y, x, p, po);
    else if (wave == 1) loc_pv<1>(vimg, y, x, p, po);
    else if (wave == 2) loc_pv<2>(vimg, y, x, p, po);
    else loc_pv<3>(vimg, y, x, p, po);

    if (wave < 2) {
#pragma unroll
        for (int o = 0; o < 64; ++o) pob[wave][lane][o] = po[o];
    }
    __syncthreads();
    if (wave >= 2) {
#pragma unroll
        for (int o = 0; o < 64; ++o) pob[wave - 2][lane][o] += po[o];
    }
    __syncthreads();

    {
        const float* stq = st + wave * 16;
        size_t base = ((size_t)(bh * NTOK + TEXTN + qq)) * DHEAD + wave * 16;
#pragma unroll
        for (int g = 0; g < 4; ++g) {
            float4 tv = *(const float4*)(stq + g * 4);
            float4 a0 = *(const float4*)&pob[0][lane][wave * 16 + g * 4];
            float4 a1 = *(const float4*)&pob[1][lane][wave * 16 + g * 4];
            float v0 = (a0.x + a1.x + cc * tv.x) * inv;
            float v1 = (a0.y + a1.y + cc * tv.y) * inv;
            float v2 = (a0.z + a1.z + cc * tv.z) * inv;
            float v3 = (a0.w + a1.w + cc * tv.w) * inv;
            ushort4 oh, ol;
            oh.x = f2bf(v0); ol.x = f2bf(v0 - bf2f(oh.x));
            oh.y = f2bf(v1); ol.y = f2bf(v1 - bf2f(oh.y));
            oh.z = f2bf(v2); ol.z = f2bf(v2 - bf2f(oh.z));
            oh.w = f2bf(v3); ol.w = f2bf(v3 - bf2f(oh.w));
            *(ushort4*)(ahi + base + g * 4) = oh;
            *(ushort4*)(alo + base + g * 4) = ol;
        }
    }
}

// ---------------- K4: out GEMM via split-bf16 MFMA ------------------------
__global__ __launch_bounds__(256) void gemm_out_mfma(const ushort* __restrict__ ahi,
                                                     const ushort* __restrict__ alo,
                                                     const ushort* __restrict__ wthi,
                                                     const ushort* __restrict__ wtlo,
                                                     const float* __restrict__ bias,
                                                     float* __restrict__ Y) {
    __shared__ __align__(16) ushort Ah[128 * LPAD], Al[128 * LPAD];
    __shared__ __align__(16) ushort Bh[64 * LPAD], Bl[64 * LPAD];
    const int tid = threadIdx.x;
    const int lane = tid & 63;
    const int w = tid >> 6;
    const int wm = w >> 1, wn = w & 1;
    const int row0 = blockIdx.y * 128;
    const int col0 = blockIdx.x * 64;

    f32x4 acc[4][2];
#pragma unroll
    for (int a = 0; a < 4; ++a)
#pragma unroll
        for (int b = 0; b < 2; ++b) acc[a][b] = (f32x4){0.f, 0.f, 0.f, 0.f};

    const int arow = tid >> 1;
    const int akb = (tid & 1) * 16;
    const int brow = tid >> 2;
    const int bkb = (tid & 3) * 8;
    const int kf = (lane >> 4) * 8;
    const int lr = lane & 15;

    const int ar = row0 + arow;
    const int a_bi = ar / NTOK;
    const int a_tok = ar - a_bi * NTOK;

    for (int k0 = 0; k0 < DIM; k0 += 32) {
        {
            const int kg = k0 + akb;
            const int hh = kg >> 6, d0 = kg & 63;
            const size_t g = ((size_t)(a_bi * 8 + hh) * NTOK + a_tok) * DHEAD + d0;
            *(bf16x8*)&Ah[arow * LPAD + akb] = *(const bf16x8*)(ahi + g);
            *(bf16x8*)&Ah[arow * LPAD + akb + 8] = *(const bf16x8*)(ahi + g + 8);
            *(bf16x8*)&Al[arow * LPAD + akb] = *(const bf16x8*)(alo + g);
            *(bf16x8*)&Al[arow * LPAD + akb + 8] = *(const bf16x8*)(alo + g + 8);
        }
        {
            const size_t g = (size_t)(col0 + brow) * DIM + k0 + bkb;
            *(bf16x8*)&Bh[brow * LPAD + bkb] = *(const bf16x8*)(wthi + g);
            *(bf16x8*)&Bl[brow * LPAD + bkb] = *(const bf16x8*)(wtlo + g);
        }
        __syncthreads();
        bf16x8 ah[4], al[4], bh[2], bl[2];
#pragma unroll
        for (int mi = 0; mi < 4; ++mi) {
            int rr = wm * 64 + mi * 16 + lr;
            ah[mi] = *(const bf16x8*)&Ah[rr * LPAD + kf];
            al[mi] = *(const bf16x8*)&Al[rr * LPAD + kf];
        }
#pragma unroll
        for (int ni = 0; ni < 2; ++ni) {
            int rr = wn * 32 + ni * 16 + lr;
            bh[ni] = *(const bf16x8*)&Bh[rr * LPAD + kf];
            bl[ni] = *(const bf16x8*)&Bl[rr * LPAD + kf];
        }
#pragma unroll
        for (int mi = 0; mi < 4; ++mi)
#pragma unroll
            for (int ni = 0; ni < 2; ++ni) {
                acc[mi][ni] = __builtin_amdgcn_mfma_f32_16x16x32_bf16(ah[mi], bh[ni], acc[mi][ni], 0, 0, 0);
                acc[mi][ni] = __builtin_amdgcn_mfma_f32_16x16x32_bf16(ah[mi], bl[ni], acc[mi][ni], 0, 0, 0);
                acc[mi][ni] = __builtin_amdgcn_mfma_f32_16x16x32_bf16(al[mi], bh[ni], acc[mi][ni], 0, 0, 0);
            }
        __syncthreads();
    }

#pragma unroll
    for (int mi = 0; mi < 4; ++mi)
#pragma unroll
        for (int ni = 0; ni < 2; ++ni) {
            int cidx = col0 + wn * 32 + ni * 16 + (lane & 15);
            float bv = bias[cidx];
#pragma unroll
            for (int j = 0; j < 4; ++j) {
                int r = row0 + wm * 64 + mi * 16 + (lane >> 4) * 4 + j;
                Y[(size_t)r * DIM + cidx] = acc[mi][ni][j] + bv;
            }
        }
}

extern "C" void kernel_launch(void* const* d_in, const int* in_sizes, int n_in,
                              void* d_out, int out_size, void* d_ws, size_t ws_size,
                              hipStream_t stream) {
    const float* x = (const float*)d_in[0];
    const float* w_qkv = (const float*)d_in[1];
    const float* w_out = (const float*)d_in[2];
    const float* b_out = (const float*)d_in[3];
    float* Y = (float*)d_out;
    float* ws = (float*)d_ws;
    float* qh = ws;
    float* kh = ws + (size_t)SEG;
    float* vh = ws + 2 * (size_t)SEG;
    float* tstate = ws + 3 * (size_t)SEG;
    ushort* xhi = (ushort*)(ws + 3 * (size_t)SEG + TSTATE_F);
    ushort* xlo = xhi + (size_t)SEG;
    ushort* ahi = xhi;  // alias: x dead after gemm_qkv; attn written after
    ushort* alo = xlo;
    ushort* wqthi = xlo + (size_t)SEG;
    ushort* wqtlo = wqthi + (size_t)DIM * NQKV;
    ushort* wothi = wqtlo + (size_t)DIM * NQKV;
    ushort* wotlo = wothi + (size_t)DIM * DIM;

    hipLaunchKernelGGL(prep_x_k, dim3(SEG / 1024), dim3(256), 0, stream, x, xhi, xlo);
    hipLaunchKernelGGL(prep_wt_k, dim3(NQKV / 32, DIM / 32), dim3(256), 0, stream,
                       w_qkv, wqthi, wqtlo, DIM, NQKV);
    hipLaunchKernelGGL(prep_wt_k, dim3(DIM / 32, DIM / 32), dim3(256), 0, stream,
                       w_out, wothi, wotlo, DIM, DIM);
    hipLaunchKernelGGL(gemm_qkv_mfma, dim3(NQKV / 64, 2304 / 128), dim3(256), 0, stream,
                       xhi, xlo, wqthi, wqtlo, qh, kh, vh);
    hipLaunchKernelGGL(attn_text_k, dim3(NBH * 36), dim3(256), 0, stream,
                       qh, kh, vh, ahi, alo, tstate);
    hipLaunchKernelGGL(attn_img_k, dim3(NBH * 16), dim3(256), 0, stream,
                       qh, kh, vh, ahi, alo, tstate);
    hipLaunchKernelGGL(gemm_out_mfma, dim3(DIM / 64, 2304 / 128), dim3(256), 0, stream,
                       ahi, alo, wothi, wotlo, b_out, Y);
}

// Round 12
// 132.304 us; speedup vs baseline: 6.7941x; 1.1129x over previous
//
#include <hip/hip_runtime.h>
#include <hip/hip_bf16.h>
#include <math.h>

#define NTOK 1152
#define DIM 512
#define NQKV 1536
#define DHEAD 64
#define NBH 16
#define TEXTN 128
#define IMGLEN 1024
#define SEG (NBH * NTOK * DHEAD)  // 1179648
#define STF 68
#define TSTATE_F (NBH * IMGLEN * STF)
#define LPAD 40
#define KTSZ (NBH * TEXTN * DHEAD)  // 131072

typedef __attribute__((ext_vector_type(8))) short bf16x8;
typedef __attribute__((ext_vector_type(4))) float f32x4;

__device__ __forceinline__ ushort f2bf(float f) {
    unsigned u = __float_as_uint(f);
    unsigned r = (u + 0x7FFFu + ((u >> 16) & 1u)) >> 16;  // RNE
    return (ushort)r;
}
__device__ __forceinline__ float bf2f(ushort u) {
    return __uint_as_float(((unsigned)u) << 16);
}

// ---------------- P1: x -> x_hi/x_lo bf16 ---------------------------------
__global__ __launch_bounds__(256) void prep_x_k(const float* __restrict__ X,
                                                ushort* __restrict__ xhi,
                                                ushort* __restrict__ xlo) {
    int i = (blockIdx.x * 256 + threadIdx.x) * 4;
    float4 v = *(const float4*)(X + i);
    ushort4 h, l;
    h.x = f2bf(v.x); l.x = f2bf(v.x - bf2f(h.x));
    h.y = f2bf(v.y); l.y = f2bf(v.y - bf2f(h.y));
    h.z = f2bf(v.z); l.z = f2bf(v.z - bf2f(h.z));
    h.w = f2bf(v.w); l.w = f2bf(v.w - bf2f(h.w));
    *(ushort4*)(xhi + i) = h;
    *(ushort4*)(xlo + i) = l;
}

// ---------------- P2: W[K][N] -> Wt_hi/lo[N][K] bf16 ----------------------
__global__ __launch_bounds__(256) void prep_wt_k(const float* __restrict__ W,
                                                 ushort* __restrict__ thi,
                                                 ushort* __restrict__ tlo,
                                                 int K, int N) {
    __shared__ float tile[32][33];
    const int bx = blockIdx.x, by = blockIdx.y;
    const int c = threadIdx.x & 31, r8 = threadIdx.x >> 5;
#pragma unroll
    for (int i = 0; i < 4; ++i) {
        int rr = r8 + i * 8;
        tile[rr][c] = W[(size_t)(by * 32 + rr) * N + bx * 32 + c];
    }
    __syncthreads();
#pragma unroll
    for (int i = 0; i < 4; ++i) {
        int rr = r8 + i * 8;
        float v = tile[c][rr];
        size_t o = (size_t)(bx * 32 + rr) * K + by * 32 + c;
        ushort h = f2bf(v);
        thi[o] = h;
        tlo[o] = f2bf(v - bf2f(h));
    }
}

// ---------------- K1: qkv GEMM via split-bf16 MFMA ------------------------
// Epilogue also emits: q as bf16 hi/lo (scaled), text-K hi/lo [bh][128][64],
// text-V hi/lo TRANSPOSED [bh][64][128] for the MFMA attention.
__global__ __launch_bounds__(256) void gemm_qkv_mfma(const ushort* __restrict__ xhi,
                                                     const ushort* __restrict__ xlo,
                                                     const ushort* __restrict__ wthi,
                                                     const ushort* __restrict__ wtlo,
                                                     float* __restrict__ qh,
                                                     float* __restrict__ kh,
                                                     float* __restrict__ vh,
                                                     ushort* __restrict__ qhi,
                                                     ushort* __restrict__ qlo,
                                                     ushort* __restrict__ kthi,
                                                     ushort* __restrict__ ktlo,
                                                     ushort* __restrict__ vthi,
                                                     ushort* __restrict__ vtlo) {
    __shared__ __align__(16) ushort Ah[128 * LPAD], Al[128 * LPAD];
    __shared__ __align__(16) ushort Bh[64 * LPAD], Bl[64 * LPAD];
    const int tid = threadIdx.x;
    const int lane = tid & 63;
    const int w = tid >> 6;
    const int wm = w >> 1, wn = w & 1;
    const int row0 = blockIdx.y * 128;
    const int col0 = blockIdx.x * 64;

    f32x4 acc[4][2];
#pragma unroll
    for (int a = 0; a < 4; ++a)
#pragma unroll
        for (int b = 0; b < 2; ++b) acc[a][b] = (f32x4){0.f, 0.f, 0.f, 0.f};

    const int arow = tid >> 1;
    const int akb = (tid & 1) * 16;
    const int brow = tid >> 2;
    const int bkb = (tid & 3) * 8;
    const int kf = (lane >> 4) * 8;
    const int lr = lane & 15;

    for (int k0 = 0; k0 < DIM; k0 += 32) {
        {
            const size_t g = (size_t)(row0 + arow) * DIM + k0 + akb;
            *(bf16x8*)&Ah[arow * LPAD + akb] = *(const bf16x8*)(xhi + g);
            *(bf16x8*)&Ah[arow * LPAD + akb + 8] = *(const bf16x8*)(xhi + g + 8);
            *(bf16x8*)&Al[arow * LPAD + akb] = *(const bf16x8*)(xlo + g);
            *(bf16x8*)&Al[arow * LPAD + akb + 8] = *(const bf16x8*)(xlo + g + 8);
        }
        {
            const size_t g = (size_t)(col0 + brow) * DIM + k0 + bkb;
            *(bf16x8*)&Bh[brow * LPAD + bkb] = *(const bf16x8*)(wthi + g);
            *(bf16x8*)&Bl[brow * LPAD + bkb] = *(const bf16x8*)(wtlo + g);
        }
        __syncthreads();
        bf16x8 ah[4], al[4], bh[2], bl[2];
#pragma unroll
        for (int mi = 0; mi < 4; ++mi) {
            int rr = wm * 64 + mi * 16 + lr;
            ah[mi] = *(const bf16x8*)&Ah[rr * LPAD + kf];
            al[mi] = *(const bf16x8*)&Al[rr * LPAD + kf];
        }
#pragma unroll
        for (int ni = 0; ni < 2; ++ni) {
            int rr = wn * 32 + ni * 16 + lr;
            bh[ni] = *(const bf16x8*)&Bh[rr * LPAD + kf];
            bl[ni] = *(const bf16x8*)&Bl[rr * LPAD + kf];
        }
#pragma unroll
        for (int mi = 0; mi < 4; ++mi)
#pragma unroll
            for (int ni = 0; ni < 2; ++ni) {
                acc[mi][ni] = __builtin_amdgcn_mfma_f32_16x16x32_bf16(ah[mi], bh[ni], acc[mi][ni], 0, 0, 0);
                acc[mi][ni] = __builtin_amdgcn_mfma_f32_16x16x32_bf16(ah[mi], bl[ni], acc[mi][ni], 0, 0, 0);
                acc[mi][ni] = __builtin_amdgcn_mfma_f32_16x16x32_bf16(al[mi], bh[ni], acc[mi][ni], 0, 0, 0);
            }
        __syncthreads();
    }

    const int which = col0 >> 9;
    const int hh = (col0 & 511) >> 6;
    const float scale = (which == 0) ? 0.125f : 1.f;
    float* dst = (which == 0) ? qh : ((which == 1) ? kh : vh);
#pragma unroll
    for (int mi = 0; mi < 4; ++mi)
#pragma unroll
        for (int ni = 0; ni < 2; ++ni)
#pragma unroll
            for (int j = 0; j < 4; ++j) {
                int r = row0 + wm * 64 + mi * 16 + (lane >> 4) * 4 + j;
                int b_i = r / NTOK, tok = r - b_i * NTOK;
                int d = wn * 32 + ni * 16 + (lane & 15);
                int bhi = b_i * 8 + hh;
                float val = acc[mi][ni][j] * scale;
                dst[((size_t)bhi * NTOK + tok) * DHEAD + d] = val;
                if (which == 0) {
                    size_t qo = ((size_t)bhi * NTOK + tok) * DHEAD + d;
                    ushort h2 = f2bf(val);
                    qhi[qo] = h2;
                    qlo[qo] = f2bf(val - bf2f(h2));
                } else if (tok >= IMGLEN) {
                    int tr = tok - IMGLEN;
                    ushort h2 = f2bf(val);
                    ushort l2 = f2bf(val - bf2f(h2));
                    if (which == 1) {
                        size_t ko = ((size_t)bhi * TEXTN + tr) * DHEAD + d;
                        kthi[ko] = h2; ktlo[ko] = l2;
                    } else {
                        size_t vo = ((size_t)bhi * DHEAD + d) * TEXTN + tr;
                        vthi[vo] = h2; vtlo[vo] = l2;
                    }
                }
            }
}

// ---------------- K2: text-key attention via MFMA (all 1152 rows) ---------
// grid = 16 bh x 18 row-tiles(64). 4 waves; wave owns 16 q-rows.
// S = Q K^T split-bf16 (3 MFMA terms); single-pass softmax (shfl tree);
// P -> LDS bf16 hi/lo; O = P V^T(stored [d][k]) split (3 terms).
// Rows <128 (text queries): finalize to ahi/alo. Rows >=128: tstate.
__global__ __launch_bounds__(256) void attn_text_mfma(const ushort* __restrict__ qhi,
                                                      const ushort* __restrict__ qlo,
                                                      const ushort* __restrict__ kthi,
                                                      const ushort* __restrict__ ktlo,
                                                      const ushort* __restrict__ vthi,
                                                      const ushort* __restrict__ vtlo,
                                                      ushort* __restrict__ ahi,
                                                      ushort* __restrict__ alo,
                                                      float* __restrict__ tstate) {
    __shared__ __align__(16) ushort Phi[4][16][136];
    __shared__ __align__(16) ushort Plo[4][16][136];
    const int bh = blockIdx.x / 18;
    const int tile = blockIdx.x % 18;
    const int wave = threadIdx.x >> 6;
    const int lane = threadIdx.x & 63;
    const int lr = lane & 15, lg = lane >> 4;
    const int kf = lg * 8;
    const int qrow0 = tile * 64 + wave * 16;
    const int tok0 = (tile < 2 ? 1024 + tile * 64 : tile * 64) + wave * 16;

    // Q fragments (2 d-steps)
    bf16x8 qah[2], qal[2];
    {
        const size_t qb = ((size_t)bh * NTOK + tok0 + lr) * DHEAD;
#pragma unroll
        for (int c = 0; c < 2; ++c) {
            qah[c] = *(const bf16x8*)(qhi + qb + c * 32 + kf);
            qal[c] = *(const bf16x8*)(qlo + qb + c * 32 + kf);
        }
    }
    // S = Q K^T over 8 key-tiles
    f32x4 s[8];
#pragma unroll
    for (int t = 0; t < 8; ++t) s[t] = (f32x4){0.f, 0.f, 0.f, 0.f};
#pragma unroll
    for (int t = 0; t < 8; ++t) {
        const size_t kb = ((size_t)bh * TEXTN + t * 16 + lr) * DHEAD;
#pragma unroll
        for (int c = 0; c < 2; ++c) {
            bf16x8 kbh = *(const bf16x8*)(kthi + kb + c * 32 + kf);
            bf16x8 kbl = *(const bf16x8*)(ktlo + kb + c * 32 + kf);
            s[t] = __builtin_amdgcn_mfma_f32_16x16x32_bf16(qah[c], kbh, s[t], 0, 0, 0);
            s[t] = __builtin_amdgcn_mfma_f32_16x16x32_bf16(qah[c], kbl, s[t], 0, 0, 0);
            s[t] = __builtin_amdgcn_mfma_f32_16x16x32_bf16(qal[c], kbh, s[t], 0, 0, 0);
        }
    }
    // row softmax: lane holds cols {t*16+lr}, rows lg*4+r
    float mx[4], sm[4];
#pragma unroll
    for (int r = 0; r < 4; ++r) {
        float v = s[0][r];
#pragma unroll
        for (int t = 1; t < 8; ++t) v = fmaxf(v, s[t][r]);
        mx[r] = v;
    }
#pragma unroll
    for (int msk = 1; msk <= 8; msk <<= 1)
#pragma unroll
        for (int r = 0; r < 4; ++r) mx[r] = fmaxf(mx[r], __shfl_xor(mx[r], msk));
#pragma unroll
    for (int r = 0; r < 4; ++r) sm[r] = 0.f;
#pragma unroll
    for (int t = 0; t < 8; ++t)
#pragma unroll
        for (int r = 0; r < 4; ++r) {
            float p = __expf(s[t][r] - mx[r]);
            s[t][r] = p;
            sm[r] += p;
        }
#pragma unroll
    for (int msk = 1; msk <= 8; msk <<= 1)
#pragma unroll
        for (int r = 0; r < 4; ++r) sm[r] += __shfl_xor(sm[r], msk);
    // P -> LDS as bf16 hi/lo
#pragma unroll
    for (int t = 0; t < 8; ++t)
#pragma unroll
        for (int r = 0; r < 4; ++r) {
            float p = s[t][r];
            ushort h = f2bf(p);
            Phi[wave][lg * 4 + r][t * 16 + lr] = h;
            Plo[wave][lg * 4 + r][t * 16 + lr] = f2bf(p - bf2f(h));
        }
    __syncthreads();
    // O = P V  (V stored transposed [bh][d][k])
    f32x4 o[4];
#pragma unroll
    for (int dt = 0; dt < 4; ++dt) o[dt] = (f32x4){0.f, 0.f, 0.f, 0.f};
#pragma unroll
    for (int c = 0; c < 4; ++c) {
        bf16x8 pah = *(const bf16x8*)&Phi[wave][lr][c * 32 + kf];
        bf16x8 pal = *(const bf16x8*)&Plo[wave][lr][c * 32 + kf];
#pragma unroll
        for (int dt = 0; dt < 4; ++dt) {
            const size_t vb = ((size_t)bh * DHEAD + dt * 16 + lr) * TEXTN + c * 32 + kf;
            bf16x8 vbh = *(const bf16x8*)(vthi + vb);
            bf16x8 vbl = *(const bf16x8*)(vtlo + vb);
            o[dt] = __builtin_amdgcn_mfma_f32_16x16x32_bf16(pah, vbh, o[dt], 0, 0, 0);
            o[dt] = __builtin_amdgcn_mfma_f32_16x16x32_bf16(pah, vbl, o[dt], 0, 0, 0);
            o[dt] = __builtin_amdgcn_mfma_f32_16x16x32_bf16(pal, vbh, o[dt], 0, 0, 0);
        }
    }
    // epilogue: lane holds O[row=qrow0+lg*4+r][d=dt*16+lr]
    if (tile < 2) {
#pragma unroll
        for (int r = 0; r < 4; ++r) {
            const int row = qrow0 + lg * 4 + r;
            const float inv = 1.f / sm[r];
            const size_t base = ((size_t)bh * NTOK + row) * DHEAD;
#pragma unroll
            for (int dt = 0; dt < 4; ++dt) {
                float v = o[dt][r] * inv;
                ushort h = f2bf(v);
                ahi[base + dt * 16 + lr] = h;
                alo[base + dt * 16 + lr] = f2bf(v - bf2f(h));
            }
        }
    } else {
#pragma unroll
        for (int r = 0; r < 4; ++r) {
            const int imgq = qrow0 - TEXTN + lg * 4 + r;
            float* st = tstate + ((size_t)bh * IMGLEN + imgq) * STF;
#pragma unroll
            for (int dt = 0; dt < 4; ++dt) st[dt * 16 + lr] = o[dt][r];
            if (lr == 0) { st[64] = mx[r]; st[65] = sm[r]; }
        }
    }
}

// ---------------- K3: img local 25-slot part, wave-split by K/V quarter ---
template <int W>
__device__ inline void loc_dots(const float* __restrict__ kimg, int y, int x,
                                const float (&q)[64], float (&sd)[25]) {
#pragma unroll
    for (int t = 0; t < 25; ++t) {
        const int ny = y + t / 5 - 2;
        const int nx = x + t % 5 - 2;
        if (ny >= 0 && ny < 32 && nx >= 0 && nx < 32) {
            const float* kp = kimg + (size_t)(ny * 32 + nx) * DHEAD + W * 16;
#pragma unroll
            for (int g = 0; g < 4; ++g) {
                float4 kv = *(const float4*)(kp + g * 4);
                float ke[4] = {kv.x, kv.y, kv.z, kv.w};
#pragma unroll
                for (int e = 0; e < 4; ++e) {
                    const int d = W * 16 + g * 4 + e;
                    const int id2 = d * 25 + t;
                    sd[id2 >> 6] += q[id2 & 63] * ke[e];
                }
            }
        }
    }
}

template <int W>
__device__ inline void loc_pv(const float* __restrict__ vimg, int y, int x,
                              const float (&p)[25], float (&po)[64]) {
#pragma unroll
    for (int t = 0; t < 25; ++t) {
        const int ny = y + t / 5 - 2;
        const int nx = x + t % 5 - 2;
        if (ny >= 0 && ny < 32 && nx >= 0 && nx < 32) {
            const float* vp = vimg + (size_t)(ny * 32 + nx) * DHEAD + W * 16;
#pragma unroll
            for (int g = 0; g < 4; ++g) {
                float4 vv = *(const float4*)(vp + g * 4);
                float ve[4] = {vv.x, vv.y, vv.z, vv.w};
#pragma unroll
                for (int e = 0; e < 4; ++e) {
                    const int d = W * 16 + g * 4 + e;
                    const int id2 = d * 25 + t;
                    po[id2 & 63] += p[id2 >> 6] * ve[e];
                }
            }
        }
    }
}

__global__ __launch_bounds__(256) void attn_img_k(const float* __restrict__ qh,
                                                  const float* __restrict__ kh,
                                                  const float* __restrict__ vh,
                                                  ushort* __restrict__ ahi,
                                                  ushort* __restrict__ alo,
                                                  const float* __restrict__ tstate) {
    __shared__ float sdb[4][64][27];
    __shared__ float pob[2][64][68];
    const int bh = blockIdx.x >> 4;
    const int qtile = (blockIdx.x & 15) << 6;
    const int wave = threadIdx.x >> 6;
    const int lane = threadIdx.x & 63;
    const int qq = qtile + lane;
    const int y = qq >> 5, x = qq & 31;
    const float* kimg = kh + (size_t)(bh * NTOK + TEXTN) * DHEAD;
    const float* vimg = vh + (size_t)(bh * NTOK + TEXTN) * DHEAD;
    const float* st = tstate + ((size_t)(bh * IMGLEN + qq)) * STF;

    float sd[25];
#pragma unroll
    for (int j = 0; j < 25; ++j) sd[j] = 0.f;
    {
        float q[64];
        const float* qp = qh + ((size_t)(bh * NTOK + TEXTN + qq)) * DHEAD;
#pragma unroll
        for (int g = 0; g < 16; ++g) {
            float4 v4 = *(const float4*)(qp + g * 4);
            q[g * 4] = v4.x; q[g * 4 + 1] = v4.y; q[g * 4 + 2] = v4.z; q[g * 4 + 3] = v4.w;
        }
        if (wave == 0) loc_dots<0>(kimg, y, x, q, sd);
        else if (wave == 1) loc_dots<1>(kimg, y, x, q, sd);
        else if (wave == 2) loc_dots<2>(kimg, y, x, q, sd);
        else loc_dots<3>(kimg, y, x, q, sd);
    }
#pragma unroll
    for (int j = 0; j < 25; ++j) sdb[wave][lane][j] = sd[j];
    __syncthreads();

    float p[25];
#pragma unroll
    for (int j = 0; j < 25; ++j)
        p[j] = (sdb[0][lane][j] + sdb[1][lane][j]) + (sdb[2][lane][j] + sdb[3][lane][j]);
    float m = st[64], l = st[65];
    float mloc = -1e30f;
#pragma unroll
    for (int j = 0; j < 25; ++j) {
        const int my = y + j / 5 - 2;
        const int mx = x + j % 5 - 2;
        bool inb = (my >= 0 && my < 32 && mx >= 0 && mx < 32);
        bool keep = inb ? (qq <= my * 32 + mx) : true;
        p[j] = keep ? p[j] : -1e30f;
        mloc = fmaxf(mloc, p[j]);
    }
    const float M = fmaxf(m, mloc);
    const float cc = __expf(m - M);
    l *= cc;
#pragma unroll
    for (int j = 0; j < 25; ++j) {
        p[j] = __expf(p[j] - M);
        l += p[j];
    }
    const float inv = 1.f / l;

    float po[64];
#pragma unroll
    for (int o = 0; o < 64; ++o) po[o] = 0.f;
    if (wave == 0) loc_pv<0>(vimg, y, x, p, po);
    else if (wave == 1) loc_pv<1>(vimg, y, x, p, po);
    else if (wave == 2) loc_pv<2>(vimg, y, x, p, po);
    else loc_pv<3>(vimg, y, x, p, po);

    if (wave < 2) {
#pragma unroll
        for (int o = 0; o < 64; ++o) pob[wave][lane][o] = po[o];
    }
    __syncthreads();
    if (wave >= 2) {
#pragma unroll
        for (int o = 0; o < 64; ++o) pob[wave - 2][lane][o] += po[o];
    }
    __syncthreads();

    {
        const float* stq = st + wave * 16;
        size_t base = ((size_t)(bh * NTOK + TEXTN + qq)) * DHEAD + wave * 16;
#pragma unroll
        for (int g = 0; g < 4; ++g) {
            float4 tv = *(const float4*)(stq + g * 4);
            float4 a0 = *(const float4*)&pob[0][lane][wave * 16 + g * 4];
            float4 a1 = *(const float4*)&pob[1][lane][wave * 16 + g * 4];
            float v0 = (a0.x + a1.x + cc * tv.x) * inv;
            float v1 = (a0.y + a1.y + cc * tv.y) * inv;
            float v2 = (a0.z + a1.z + cc * tv.z) * inv;
            float v3 = (a0.w + a1.w + cc * tv.w) * inv;
            ushort4 oh, ol;
            oh.x = f2bf(v0); ol.x = f2bf(v0 - bf2f(oh.x));
            oh.y = f2bf(v1); ol.y = f2bf(v1 - bf2f(oh.y));
            oh.z = f2bf(v2); ol.z = f2bf(v2 - bf2f(oh.z));
            oh.w = f2bf(v3); ol.w = f2bf(v3 - bf2f(oh.w));
            *(ushort4*)(ahi + base + g * 4) = oh;
            *(ushort4*)(alo + base + g * 4) = ol;
        }
    }
}

// ---------------- K4: out GEMM via split-bf16 MFMA ------------------------
__global__ __launch_bounds__(256) void gemm_out_mfma(const ushort* __restrict__ ahi,
                                                     const ushort* __restrict__ alo,
                                                     const ushort* __restrict__ wthi,
                                                     const ushort* __restrict__ wtlo,
                                                     const float* __restrict__ bias,
                                                     float* __restrict__ Y) {
    __shared__ __align__(16) ushort Ah[128 * LPAD], Al[128 * LPAD];
    __shared__ __align__(16) ushort Bh[64 * LPAD], Bl[64 * LPAD];
    const int tid = threadIdx.x;
    const int lane = tid & 63;
    const int w = tid >> 6;
    const int wm = w >> 1, wn = w & 1;
    const int row0 = blockIdx.y * 128;
    const int col0 = blockIdx.x * 64;

    f32x4 acc[4][2];
#pragma unroll
    for (int a = 0; a < 4; ++a)
#pragma unroll
        for (int b = 0; b < 2; ++b) acc[a][b] = (f32x4){0.f, 0.f, 0.f, 0.f};

    const int arow = tid >> 1;
    const int akb = (tid & 1) * 16;
    const int brow = tid >> 2;
    const int bkb = (tid & 3) * 8;
    const int kf = (lane >> 4) * 8;
    const int lr = lane & 15;

    const int ar = row0 + arow;
    const int a_bi = ar / NTOK;
    const int a_tok = ar - a_bi * NTOK;

    for (int k0 = 0; k0 < DIM; k0 += 32) {
        {
            const int kg = k0 + akb;
            const int hh = kg >> 6, d0 = kg & 63;
            const size_t g = ((size_t)(a_bi * 8 + hh) * NTOK + a_tok) * DHEAD + d0;
            *(bf16x8*)&Ah[arow * LPAD + akb] = *(const bf16x8*)(ahi + g);
            *(bf16x8*)&Ah[arow * LPAD + akb + 8] = *(const bf16x8*)(ahi + g + 8);
            *(bf16x8*)&Al[arow * LPAD + akb] = *(const bf16x8*)(alo + g);
            *(bf16x8*)&Al[arow * LPAD + akb + 8] = *(const bf16x8*)(alo + g + 8);
        }
        {
            const size_t g = (size_t)(col0 + brow) * DIM + k0 + bkb;
            *(bf16x8*)&Bh[brow * LPAD + bkb] = *(const bf16x8*)(wthi + g);
            *(bf16x8*)&Bl[brow * LPAD + bkb] = *(const bf16x8*)(wtlo + g);
        }
        __syncthreads();
        bf16x8 ah[4], al[4], bh[2], bl[2];
#pragma unroll
        for (int mi = 0; mi < 4; ++mi) {
            int rr = wm * 64 + mi * 16 + lr;
            ah[mi] = *(const bf16x8*)&Ah[rr * LPAD + kf];
            al[mi] = *(const bf16x8*)&Al[rr * LPAD + kf];
        }
#pragma unroll
        for (int ni = 0; ni < 2; ++ni) {
            int rr = wn * 32 + ni * 16 + lr;
            bh[ni] = *(const bf16x8*)&Bh[rr * LPAD + kf];
            bl[ni] = *(const bf16x8*)&Bl[rr * LPAD + kf];
        }
#pragma unroll
        for (int mi = 0; mi < 4; ++mi)
#pragma unroll
            for (int ni = 0; ni < 2; ++ni) {
                acc[mi][ni] = __builtin_amdgcn_mfma_f32_16x16x32_bf16(ah[mi], bh[ni], acc[mi][ni], 0, 0, 0);
                acc[mi][ni] = __builtin_amdgcn_mfma_f32_16x16x32_bf16(ah[mi], bl[ni], acc[mi][ni], 0, 0, 0);
                acc[mi][ni] = __builtin_amdgcn_mfma_f32_16x16x32_bf16(al[mi], bh[ni], acc[mi][ni], 0, 0, 0);
            }
        __syncthreads();
    }

#pragma unroll
    for (int mi = 0; mi < 4; ++mi)
#pragma unroll
        for (int ni = 0; ni < 2; ++ni) {
            int cidx = col0 + wn * 32 + ni * 16 + (lane & 15);
            float bv = bias[cidx];
#pragma unroll
            for (int j = 0; j < 4; ++j) {
                int r = row0 + wm * 64 + mi * 16 + (lane >> 4) * 4 + j;
                Y[(size_t)r * DIM + cidx] = acc[mi][ni][j] + bv;
            }
        }
}

extern "C" void kernel_launch(void* const* d_in, const int* in_sizes, int n_in,
                              void* d_out, int out_size, void* d_ws, size_t ws_size,
                              hipStream_t stream) {
    const float* x = (const float*)d_in[0];
    const float* w_qkv = (const float*)d_in[1];
    const float* w_out = (const float*)d_in[2];
    const float* b_out = (const float*)d_in[3];
    float* Y = (float*)d_out;
    float* ws = (float*)d_ws;
    float* qh = ws;
    float* kh = ws + (size_t)SEG;
    float* vh = ws + 2 * (size_t)SEG;
    float* tstate = ws + 3 * (size_t)SEG;
    ushort* xhi = (ushort*)(ws + 3 * (size_t)SEG + TSTATE_F);
    ushort* xlo = xhi + (size_t)SEG;
    ushort* ahi = xhi;  // alias: x dead after gemm_qkv; attn written after
    ushort* alo = xlo;
    ushort* wqthi = xlo + (size_t)SEG;
    ushort* wqtlo = wqthi + (size_t)DIM * NQKV;
    ushort* wothi = wqtlo + (size_t)DIM * NQKV;
    ushort* wotlo = wothi + (size_t)DIM * DIM;
    ushort* qhi = wotlo + (size_t)DIM * DIM;
    ushort* qlo = qhi + (size_t)SEG;
    ushort* kthi = qlo + (size_t)SEG;
    ushort* ktlo = kthi + (size_t)KTSZ;
    ushort* vthi = ktlo + (size_t)KTSZ;
    ushort* vtlo = vthi + (size_t)KTSZ;

    hipLaunchKernelGGL(prep_x_k, dim3(SEG / 1024), dim3(256), 0, stream, x, xhi, xlo);
    hipLaunchKernelGGL(prep_wt_k, dim3(NQKV / 32, DIM / 32), dim3(256), 0, stream,
                       w_qkv, wqthi, wqtlo, DIM, NQKV);
    hipLaunchKernelGGL(prep_wt_k, dim3(DIM / 32, DIM / 32), dim3(256), 0, stream,
                       w_out, wothi, wotlo, DIM, DIM);
    hipLaunchKernelGGL(gemm_qkv_mfma, dim3(NQKV / 64, 2304 / 128), dim3(256), 0, stream,
                       xhi, xlo, wqthi, wqtlo, qh, kh, vh,
                       qhi, qlo, kthi, ktlo, vthi, vtlo);
    hipLaunchKernelGGL(attn_text_mfma, dim3(NBH * 18), dim3(256), 0, stream,
                       qhi, qlo, kthi, ktlo, vthi, vtlo, ahi, alo, tstate);
    hipLaunchKernelGGL(attn_img_k, dim3(NBH * 16), dim3(256), 0, stream,
                       qh, kh, vh, ahi, alo, tstate);
    hipLaunchKernelGGL(gemm_out_mfma, dim3(DIM / 64, 2304 / 128), dim3(256), 0, stream,
                       ahi, alo, wothi, wotlo, b_out, Y);
}